// Round 7
// baseline (368.928 us; speedup 1.0000x reference)
//
#include <hip/hip_runtime.h>
#include <hip/hip_fp16.h>

#define NG 64              // graphs (= Y feature width)
#define NGRAPH_C 64

// edge multi-split geometry
#define RSZ 12500          // nodes per range (8 ranges for n=100000)
#define RSZP 6250          // packed u16 pairs per range
#define NC_MS 64           // edge chunks
#define MSB 1024           // threads/block for count/fill (occupancy: 2 blk/CU x 16 waves)

// word contraction geometry
#define VOC 10000
#define KPAD 10240         // padded K for wgemm (80 chunks of 128)
#define NKC 80             // split-k chunks
#define WGK 128            // K per chunk

// atom-table partial geometry
#define TAB 128            // k_ta blocks
#define TAW 2624           // 41*64 entries

// ---- bit casts ----
__device__ __forceinline__ unsigned f_as_u(float f) { union { float f; unsigned u; } c; c.f = f; return c.u; }
__device__ __forceinline__ float u_as_f(unsigned u) { union { unsigned u; float f; } c; c.u = u; return c.f; }

// XCD id (0..7)
__device__ __forceinline__ int xcc_id() {
    unsigned x;
    asm volatile("s_getreg_b32 %0, hwreg(HW_REG_XCC_ID)" : "=s"(x));
    return (int)(x & 7u);
}

union H4 { uint2 u2; __half h[4]; };

// ---------------- edge multi-split count (1024 thr: latency hidden by 16 waves) ----------------
__global__ __launch_bounds__(MSB) void k_mscount(const int* __restrict__ src, const int* __restrict__ dst,
                                                 unsigned* __restrict__ rep_in,
                                                 unsigned* __restrict__ rep_src,
                                                 int e, int n, int chunk, int npairs) {
    __shared__ unsigned hin[RSZP];
    __shared__ unsigned hsrc[RSZP];
    int c = blockIdx.x % NC_MS;
    int r = blockIdx.x / NC_MS;
    int base = r * RSZ;
    int t = threadIdx.x;
    for (int w = t; w < RSZP; w += MSB) { hin[w] = 0u; hsrc[w] = 0u; }
    __syncthreads();
    int e0 = c * chunk, e1 = min(e, e0 + chunk);
    for (int i = e0 + t; i < e1; i += MSB) {
        int s = src[i], d = dst[i];
        unsigned ud = (unsigned)(d - base);
        unsigned us = (unsigned)(s - base);
        if (ud < (unsigned)RSZ) atomicAdd(&hin[ud >> 1], 1u << ((ud & 1) * 16));
        if (us < (unsigned)RSZ) atomicAdd(&hsrc[us >> 1], 1u << ((us & 1) * 16));
    }
    __syncthreads();
    int lim = min(RSZ, n - base);
    if (lim <= 0) return;
    int plim = (lim + 1) >> 1;
    unsigned* gin  = rep_in  + (size_t)c * npairs + (base >> 1);
    unsigned* gsrc = rep_src + (size_t)c * npairs + (base >> 1);
    for (int w = t; w < plim; w += MSB) { gin[w] = hin[w]; gsrc[w] = hsrc[w]; }
}

__global__ __launch_bounds__(256) void k_msreduce(const unsigned* __restrict__ rep_in,
                                                  unsigned* __restrict__ rep_src,   // -> pref
                                                  float* __restrict__ dinv,
                                                  unsigned* __restrict__ counts_src,
                                                  int n, int npairs) {
    int i2 = blockIdx.x * 256 + threadIdx.x;
    if (i2 >= npairs) return;
    unsigned slo = 0, shi = 0, rlo = 0, rhi = 0;
#pragma unroll 4
    for (int c = 0; c < NC_MS; ++c) {
        unsigned vi = rep_in[(size_t)c * npairs + i2];
        slo += vi & 0xFFFFu; shi += vi >> 16;
        unsigned vs = rep_src[(size_t)c * npairs + i2];
        rep_src[(size_t)c * npairs + i2] = rlo | (rhi << 16);
        rlo += vs & 0xFFFFu; rhi += vs >> 16;
    }
    int i = i2 * 2;
    dinv[i] = rsqrtf((float)(slo + 1u));
    counts_src[i] = rlo;
    if (i + 1 < n) {
        dinv[i + 1] = rsqrtf((float)(shi + 1u));
        counts_src[i + 1] = rhi;
    }
}

// ---------------- 2-level exclusive scan ----------------
__global__ __launch_bounds__(256) void k_blocksum(const unsigned* __restrict__ counts,
                                                  unsigned* __restrict__ partials, int n) {
    __shared__ unsigned s[256];
    int base = blockIdx.x * 1024;
    unsigned sum = 0;
    for (int j = threadIdx.x; j < 1024; j += 256) {
        int i = base + j;
        sum += (i < n) ? counts[i] : 0u;
    }
    s[threadIdx.x] = sum;
    __syncthreads();
    for (int off = 128; off > 0; off >>= 1) {
        if (threadIdx.x < (unsigned)off) s[threadIdx.x] += s[threadIdx.x + off];
        __syncthreads();
    }
    if (threadIdx.x == 0) partials[blockIdx.x] = s[0];
}

__global__ __launch_bounds__(128) void k_scanpartials(unsigned* __restrict__ partials, int nb) {
    __shared__ unsigned s[128];
    int t = threadIdx.x;
    s[t] = (t < nb) ? partials[t] : 0u;
    __syncthreads();
    if (t == 0) {
        unsigned run = 0;
        for (int i = 0; i < nb; ++i) { unsigned v = s[i]; s[i] = run; run += v; }
    }
    __syncthreads();
    if (t < nb) partials[t] = s[t];
}

__global__ __launch_bounds__(256) void k_scanblock(const unsigned* __restrict__ counts,
                                                   const unsigned* __restrict__ partials,
                                                   unsigned* __restrict__ row_start, int n) {
    __shared__ unsigned s[256];
    int base = blockIdx.x * 1024;
    int t = threadIdx.x;
    unsigned v[4];
    unsigned tsum = 0;
#pragma unroll
    for (int j = 0; j < 4; ++j) {
        int i = base + t * 4 + j;
        v[j] = (i < n) ? counts[i] : 0u;
        tsum += v[j];
    }
    s[t] = tsum;
    __syncthreads();
    for (int off = 1; off < 256; off <<= 1) {
        unsigned x = (t >= off) ? s[t - off] : 0u;
        __syncthreads();
        s[t] += x;
        __syncthreads();
    }
    unsigned excl = (t > 0 ? s[t - 1] : 0u) + partials[blockIdx.x];
#pragma unroll
    for (int j = 0; j < 4; ++j) {
        int i = base + t * 4 + j;
        if (i < n) {
            row_start[i] = excl;
            excl += v[j];
            if (i == n - 1) row_start[n] = excl;
        }
    }
}

// ---------------- edge multi-split fill (1024 thr) ----------------
__global__ __launch_bounds__(MSB) void k_msfill(const int* __restrict__ src, const int* __restrict__ dst,
                                                const int* __restrict__ batch,
                                                const unsigned* __restrict__ row_start,
                                                const unsigned* __restrict__ pref,
                                                const float* __restrict__ dinv,
                                                uint2* __restrict__ euv,
                                                int e, int n, int chunk, int npairs) {
    __shared__ unsigned cur[RSZP];
    int c = blockIdx.x % NC_MS;
    int r = blockIdx.x / NC_MS;
    int base = r * RSZ;
    int t = threadIdx.x;
    for (int w = t; w < RSZP; w += MSB) cur[w] = 0u;
    __syncthreads();
    int e0 = c * chunk, e1 = min(e, e0 + chunk);
    const unsigned* prefc = pref + (size_t)c * npairs;
    for (int i = e0 + t; i < e1; i += MSB) {
        int s = src[i];
        unsigned us = (unsigned)(s - base);
        if (us < (unsigned)RSZ) {
            int d = dst[i];
            unsigned sh = (us & 1) * 16;
            unsigned old = atomicAdd(&cur[us >> 1], 1u << sh);
            unsigned slot = (old >> sh) & 0xFFFFu;
            unsigned p16 = (prefc[(unsigned)s >> 1] >> ((s & 1) * 16)) & 0xFFFFu;
            unsigned pos = row_start[s] + p16 + slot;
            uint2 pv;
            pv.x = (unsigned)d | ((unsigned)batch[d] << 17);
            pv.y = f_as_u(dinv[s] * dinv[d]);
            euv[pos] = pv;
        }
    }
}

// ---------------- word counting sort (order-free: atomic cursor) ----------------
__global__ __launch_bounds__(256) void k_wcount(const int* __restrict__ x,
                                                unsigned* __restrict__ wcnt, int n) {
    int j = blockIdx.x * 256 + threadIdx.x;
    if (j >= n) return;
    atomicAdd(&wcnt[x[2 * j + 1]], 1u);
}

__global__ __launch_bounds__(256) void k_wfill(const int* __restrict__ x,
                                               const unsigned* __restrict__ wstart,
                                               unsigned* __restrict__ wcur,
                                               unsigned* __restrict__ sorted, int n) {
    int j = blockIdx.x * 256 + threadIdx.x;
    if (j >= n) return;
    int w = x[2 * j + 1];
    unsigned pos = wstart[w] + atomicAdd(&wcur[w], 1u);
    sorted[pos] = (unsigned)j;
}

// ---------------- per-word column sums: tw[w][g] (plain stores) ----------------
__global__ __launch_bounds__(256) void k_twfill(const __half* __restrict__ Y3,
                                                const unsigned* __restrict__ sorted,
                                                const unsigned* __restrict__ wstart,
                                                float* __restrict__ tw) {
    int w = blockIdx.x * 4 + (threadIdx.x >> 6);
    int g = threadIdx.x & 63;
    if (w >= VOC) return;
    unsigned i0 = wstart[w], i1 = wstart[w + 1];
    float s = 0.f;
    unsigned i = i0;
    for (; i + 2 <= i1; i += 2) {
        unsigned j0 = sorted[i], j1 = sorted[i + 1];
        s += __half2float(Y3[(size_t)j0 * NG + g]) + __half2float(Y3[(size_t)j1 * NG + g]);
    }
    if (i < i1) {
        unsigned j0 = sorted[i];
        s += __half2float(Y3[(size_t)j0 * NG + g]);
    }
    tw[(size_t)w * NG + g] = s;
}

// ---------------- graph boundaries (batch sorted) ----------------
__global__ __launch_bounds__(128) void k_gstart(const int* __restrict__ batch,
                                                int* __restrict__ gstart, int n, int ngraph) {
    int g = threadIdx.x;
    if (g > ngraph) return;
    if (g == ngraph) { gstart[g] = n; return; }
    int lo = 0, hi = n;
    while (lo < hi) {
        int mid = (lo + hi) >> 1;
        if (batch[mid] < g) lo = mid + 1; else hi = mid;
    }
    gstart[g] = lo;
}

// ---------------- hop 1 (fp16 out, 4-wide unrolled edge loop) ----------------
__global__ __launch_bounds__(256) void k_y1(const int* __restrict__ batch,
                                            const float* __restrict__ dinv,
                                            const unsigned* __restrict__ row_start,
                                            const uint2* __restrict__ euv,
                                            __half* __restrict__ Y1, int n) {
    int idx = blockIdx.x * 256 + threadIdx.x;
    if (idx >= n * 16) return;
    int j = idx >> 4;
    int c4 = idx & 15;
    int cb = c4 * 4;
    float a0 = 0.f, a1 = 0.f, a2 = 0.f, a3 = 0.f;
    {
        int bj = batch[j];
        float dj = dinv[j];
        float sn = dj * dj;
        a0 += (bj == cb + 0) ? sn : 0.f;
        a1 += (bj == cb + 1) ? sn : 0.f;
        a2 += (bj == cb + 2) ? sn : 0.f;
        a3 += (bj == cb + 3) ? sn : 0.f;
    }
    unsigned e0 = row_start[j], e1 = row_start[j + 1];
    unsigned e = e0;
    for (; e + 4 <= e1; e += 4) {
        uint2 p0 = euv[e], p1 = euv[e + 1], p2 = euv[e + 2], p3 = euv[e + 3];
        int b0 = (int)(p0.x >> 17), b1 = (int)(p1.x >> 17);
        int b2 = (int)(p2.x >> 17), b3 = (int)(p3.x >> 17);
        float v0 = u_as_f(p0.y), v1 = u_as_f(p1.y);
        float v2 = u_as_f(p2.y), v3 = u_as_f(p3.y);
        a0 += ((b0 == cb + 0) ? v0 : 0.f) + ((b1 == cb + 0) ? v1 : 0.f)
            + ((b2 == cb + 0) ? v2 : 0.f) + ((b3 == cb + 0) ? v3 : 0.f);
        a1 += ((b0 == cb + 1) ? v0 : 0.f) + ((b1 == cb + 1) ? v1 : 0.f)
            + ((b2 == cb + 1) ? v2 : 0.f) + ((b3 == cb + 1) ? v3 : 0.f);
        a2 += ((b0 == cb + 2) ? v0 : 0.f) + ((b1 == cb + 2) ? v1 : 0.f)
            + ((b2 == cb + 2) ? v2 : 0.f) + ((b3 == cb + 2) ? v3 : 0.f);
        a3 += ((b0 == cb + 3) ? v0 : 0.f) + ((b1 == cb + 3) ? v1 : 0.f)
            + ((b2 == cb + 3) ? v2 : 0.f) + ((b3 == cb + 3) ? v3 : 0.f);
    }
    for (; e < e1; ++e) {
        uint2 p = euv[e];
        int bd = (int)(p.x >> 17);
        float v = u_as_f(p.y);
        a0 += (bd == cb + 0) ? v : 0.f;
        a1 += (bd == cb + 1) ? v : 0.f;
        a2 += (bd == cb + 2) ? v : 0.f;
        a3 += (bd == cb + 3) ? v : 0.f;
    }
    H4 o;
    o.h[0] = __float2half(a0); o.h[1] = __float2half(a1);
    o.h[2] = __float2half(a2); o.h[3] = __float2half(a3);
    *(uint2*)&Y1[(size_t)j * NG + cb] = o.u2;
}

// ---------------- Y-hop fp16 -> fp16 (4-wide unrolled gather for MLP) ----------------
__global__ __launch_bounds__(256) void k_yprop(const __half* __restrict__ Yin,
                                               const float* __restrict__ dinv,
                                               const unsigned* __restrict__ row_start,
                                               const uint2* __restrict__ euv,
                                               __half* __restrict__ Yout, int n) {
    int idx = blockIdx.x * 256 + threadIdx.x;
    if (idx >= n * 16) return;
    int j = idx >> 4;
    int c4 = idx & 15;
    int cb = c4 * 4;
    float dj = dinv[j];
    float sn = dj * dj;
    H4 s; s.u2 = *(const uint2*)&Yin[(size_t)j * NG + cb];
    float a0 = sn * __half2float(s.h[0]);
    float a1 = sn * __half2float(s.h[1]);
    float a2 = sn * __half2float(s.h[2]);
    float a3 = sn * __half2float(s.h[3]);
    unsigned e0 = row_start[j], e1 = row_start[j + 1];
    unsigned e = e0;
    for (; e + 4 <= e1; e += 4) {
        uint2 p0 = euv[e], p1 = euv[e + 1], p2 = euv[e + 2], p3 = euv[e + 3];
        float v0 = u_as_f(p0.y), v1 = u_as_f(p1.y);
        float v2 = u_as_f(p2.y), v3 = u_as_f(p3.y);
        H4 m0; m0.u2 = *(const uint2*)&Yin[(size_t)(p0.x & 0x1FFFFu) * NG + cb];
        H4 m1; m1.u2 = *(const uint2*)&Yin[(size_t)(p1.x & 0x1FFFFu) * NG + cb];
        H4 m2; m2.u2 = *(const uint2*)&Yin[(size_t)(p2.x & 0x1FFFFu) * NG + cb];
        H4 m3; m3.u2 = *(const uint2*)&Yin[(size_t)(p3.x & 0x1FFFFu) * NG + cb];
        a0 += v0 * __half2float(m0.h[0]) + v1 * __half2float(m1.h[0])
            + v2 * __half2float(m2.h[0]) + v3 * __half2float(m3.h[0]);
        a1 += v0 * __half2float(m0.h[1]) + v1 * __half2float(m1.h[1])
            + v2 * __half2float(m2.h[1]) + v3 * __half2float(m3.h[1]);
        a2 += v0 * __half2float(m0.h[2]) + v1 * __half2float(m1.h[2])
            + v2 * __half2float(m2.h[2]) + v3 * __half2float(m3.h[2]);
        a3 += v0 * __half2float(m0.h[3]) + v1 * __half2float(m1.h[3])
            + v2 * __half2float(m2.h[3]) + v3 * __half2float(m3.h[3]);
    }
    for (; e < e1; ++e) {
        uint2 p0 = euv[e];
        float v0 = u_as_f(p0.y);
        H4 m0; m0.u2 = *(const uint2*)&Yin[(size_t)(p0.x & 0x1FFFFu) * NG + cb];
        a0 += v0 * __half2float(m0.h[0]);
        a1 += v0 * __half2float(m0.h[1]);
        a2 += v0 * __half2float(m0.h[2]);
        a3 += v0 * __half2float(m0.h[3]);
    }
    H4 o;
    o.h[0] = __float2half(a0); o.h[1] = __float2half(a1);
    o.h[2] = __float2half(a2); o.h[3] = __float2half(a3);
    *(uint2*)&Yout[(size_t)j * NG + cb] = o.u2;
}

// ---------------- column sums (fp16 input), XCC-replicated output ----------------
__global__ __launch_bounds__(256) void k_colsumh(const __half* __restrict__ Y,
                                                 float* __restrict__ su8, int n) {
    __shared__ float red[16][NG];
    int t = threadIdx.x;
    int cg = t & 15;
    int sr = t >> 4;
    float a0 = 0.f, a1 = 0.f, a2 = 0.f, a3 = 0.f;
    int stride = gridDim.x * 16;
    for (int j = blockIdx.x * 16 + sr; j < n; j += stride) {
        H4 v; v.u2 = *(const uint2*)&Y[(size_t)j * NG + cg * 4];
        a0 += __half2float(v.h[0]);
        a1 += __half2float(v.h[1]);
        a2 += __half2float(v.h[2]);
        a3 += __half2float(v.h[3]);
    }
    red[sr][cg * 4 + 0] = a0;
    red[sr][cg * 4 + 1] = a1;
    red[sr][cg * 4 + 2] = a2;
    red[sr][cg * 4 + 3] = a3;
    __syncthreads();
    if (t < NG) {
        float s = 0.f;
#pragma unroll
        for (int q = 0; q < 16; ++q) s += red[q][t];
        int r = xcc_id();
        __hip_atomic_fetch_add(&su8[r * NG + t], s,
                               __ATOMIC_RELAXED, __HIP_MEMORY_SCOPE_WORKGROUP);
    }
}

// ---------------- atom table: LDS histogram -> per-block PARTIALS (plain stores) ----------------
// The old global-atomic flush (512 same-address RMW chains over 2624 addrs) serialized
// at ~42us regardless of gather shape (r5 vs r6 A/B). Plain stores + tree reduce instead.
__global__ __launch_bounds__(1024) void k_ta(const __half* __restrict__ Y3,
                                             const int* __restrict__ x,
                                             float* __restrict__ tapart, int n) {
    __shared__ float lta[TAW];
    int t = threadIdx.x;
    for (int i = t; i < TAW; i += 1024) lta[i] = 0.f;
    __syncthreads();
    int g = t & 63;
    int sv = t >> 6;                     // 0..15
    int stride = gridDim.x * 16;
    for (int j = blockIdx.x * 16 + sv; j < n; j += stride) {
        float y = __half2float(Y3[(size_t)j * NG + g]);
        int a = x[2 * j];
        atomicAdd(&lta[a * NG + g], y);
    }
    __syncthreads();
    float* gp = tapart + (size_t)blockIdx.x * TAW;
    for (int i = t; i < TAW; i += 1024) gp[i] = lta[i];
}

// reduce TAB partials into ta (8-way split-p; 21K spread atomics)
__global__ __launch_bounds__(256) void k_tareduce(const float* __restrict__ tapart,
                                                  float* __restrict__ ta) {
    int i = blockIdx.x * 256 + threadIdx.x;
    if (i >= TAW) return;
    int p0 = blockIdx.y * (TAB / 8);
    int p1 = p0 + (TAB / 8);
    float s = 0.f;
    for (int p = p0; p < p1; ++p) s += tapart[(size_t)p * TAW + i];
    atomicAdd(&ta[i], s);
}

// ---------------- tiled word contraction: Gpart[kc] = tw_chunk^T @ wt_chunk ----------------
__global__ __launch_bounds__(256) void k_wgemm2(const float* __restrict__ T,    // [KPAD][64]
                                                const float* __restrict__ Tab,  // [10000][300]
                                                float* __restrict__ Gpart) {
    __shared__ float Asm[32 * 64];
    __shared__ float Bsm[32 * 64];
    const int t = threadIdx.x;
    const int tg = t >> 4;
    const int tc = t & 15;
    const int c0 = blockIdx.x * 64;
    const int kb = blockIdx.y * WGK;

    float acc[4][4] = {};

    for (int sub = 0; sub < WGK / 32; ++sub) {
        int kbase = kb + sub * 32;
#pragma unroll
        for (int r2 = 0; r2 < 2; ++r2) {
            int idx4 = r2 * 256 + t;
            int k = idx4 >> 4, g4 = idx4 & 15;
            float4 v = *(const float4*)&T[(size_t)(kbase + k) * 64 + g4 * 4];
            *(float4*)&Asm[k * 64 + g4 * 4] = v;
        }
#pragma unroll
        for (int r2 = 0; r2 < 2; ++r2) {
            int idx4 = r2 * 256 + t;
            int k = idx4 >> 4, c4i = idx4 & 15;
            int gk = kbase + k;
            int cb2 = c0 + c4i * 4;
            float4 v;
            if (gk < VOC && cb2 + 3 < 300) {
                v = *(const float4*)&Tab[(size_t)gk * 300 + cb2];
            } else {
                float tmp[4];
#pragma unroll
                for (int q = 0; q < 4; ++q)
                    tmp[q] = (gk < VOC && cb2 + q < 300) ? Tab[(size_t)gk * 300 + cb2 + q] : 0.f;
                v.x = tmp[0]; v.y = tmp[1]; v.z = tmp[2]; v.w = tmp[3];
            }
            *(float4*)&Bsm[k * 64 + c4i * 4] = v;
        }
        __syncthreads();
#pragma unroll 8
        for (int k = 0; k < 32; ++k) {
            float4 a4 = *(const float4*)&Asm[k * 64 + tg * 4];
            float4 b4 = *(const float4*)&Bsm[k * 64 + tc * 4];
            float a[4] = {a4.x, a4.y, a4.z, a4.w};
            float b[4] = {b4.x, b4.y, b4.z, b4.w};
#pragma unroll
            for (int i = 0; i < 4; ++i)
#pragma unroll
                for (int jj = 0; jj < 4; ++jj) acc[i][jj] += a[i] * b[jj];
        }
        __syncthreads();
    }

    float* gp = Gpart + (size_t)blockIdx.y * (NG * 300);
#pragma unroll
    for (int i = 0; i < 4; ++i) {
        int g = tg * 4 + i;
#pragma unroll
        for (int jj = 0; jj < 4; ++jj) {
            int c = c0 + tc * 4 + jj;
            if (c < 300) gp[g * 300 + c] = acc[i][jj];
        }
    }
}

// reduce k-chunk partials into G0 (few atomics; G0 zeroed)
__global__ __launch_bounds__(256) void k_greduce(const float* __restrict__ Gpart,
                                                 float* __restrict__ G0) {
    int k = blockIdx.x * 256 + threadIdx.x;
    if (k >= NG * 300) return;
    int p0 = blockIdx.y * (NKC / 8);
    int p1 = p0 + (NKC / 8);
    float s = 0.f;
    for (int p = p0; p < p1; ++p) s += Gpart[(size_t)p * (NG * 300) + k];
    atomicAdd(&G0[k], s);
}

// ---------------- atom contraction: K=41 ----------------
__global__ __launch_bounds__(256) void k_agemm(const float* __restrict__ T,
                                               const float* __restrict__ Tab,
                                               float* __restrict__ G0) {
    int j = blockIdx.x * 256 + threadIdx.x;
    if (j >= NG * 300) return;
    int g = j / 300, c = j - g * 300;
    float acc = 0.f;
#pragma unroll
    for (int k = 0; k < 41; ++k) acc += T[(size_t)k * NG + g] * Tab[(size_t)k * 300 + c];
    atomicAdd(&G0[j], acc);
}

// ---------------- small GEMM split-k ----------------
__global__ __launch_bounds__(256) void k_smm(const float* __restrict__ A,
                                             const float* __restrict__ W,
                                             float* __restrict__ C) {
    int j = blockIdx.x * 256 + threadIdx.x;
    if (j >= NG * 300) return;
    int g = j / 300, c = j - g * 300;
    int k0 = blockIdx.y * 60;
    float acc = 0.f;
#pragma unroll 1
    for (int k = k0; k < k0 + 60; k += 4) {
        float a0 = A[g * 300 + k + 0], a1 = A[g * 300 + k + 1];
        float a2 = A[g * 300 + k + 2], a3 = A[g * 300 + k + 3];
        float w0 = W[(k + 0) * 300 + c], w1 = W[(k + 1) * 300 + c];
        float w2 = W[(k + 2) * 300 + c], w3 = W[(k + 3) * 300 + c];
        acc += a0 * w0 + a1 * w1 + a2 * w2 + a3 * w3;
    }
    atomicAdd(&C[j], acc);
}

// ---------------- vector-matrix ----------------
__global__ __launch_bounds__(256) void k_vec(const float* __restrict__ vin,
                                             const float* __restrict__ W,
                                             float* __restrict__ r_out) {
    int c = blockIdx.x * 256 + threadIdx.x;
    if (c >= 300) return;
    int k0 = blockIdx.y * 75;
    float acc = 0.f;
    for (int k = k0; k < k0 + 75; ++k) acc += vin[k] * W[k * 300 + c];
    atomicAdd(&r_out[c], acc);
}

// ---------------- final assembly ----------------
__global__ __launch_bounds__(256) void k_out(const float* __restrict__ T3,
                                             const float* __restrict__ su1,
                                             const float* __restrict__ su2,
                                             const int* __restrict__ gstart,
                                             const float* __restrict__ r1,
                                             const float* __restrict__ r2,
                                             const float* __restrict__ b,
                                             float* __restrict__ out) {
    int j = blockIdx.x * 256 + threadIdx.x;
    if (j >= NG * 300) return;
    int g = j / 300, c = j - g * 300;
    int cnt = gstart[g + 1] - gstart[g];
    float s1 = 0.f, s2 = 0.f;
#pragma unroll
    for (int r = 0; r < 8; ++r) {
        s1 += su1[r * NG + g];
        s2 += su2[r * NG + g];
    }
    float v = T3[j] + s2 * r2[c] + s1 * r1[c] + (float)cnt * b[c];
    out[j] = v / (float)(cnt > 0 ? cnt : 1);
}

// ---------------- launch ----------------
extern "C" void kernel_launch(void* const* d_in, const int* in_sizes, int n_in,
                              void* d_out, int out_size, void* d_ws, size_t ws_size,
                              hipStream_t stream) {
    const int*   x     = (const int*)d_in[0];
    const int*   ei    = (const int*)d_in[1];
    const int*   batch = (const int*)d_in[2];
    const float* at    = (const float*)d_in[3];
    const float* wt    = (const float*)d_in[4];
    const float* W     = (const float*)d_in[5];
    const float* b     = (const float*)d_in[6];

    const int n = in_sizes[0] / 2;   // 100000
    const int e = in_sizes[1] / 2;   // 800000

    char* ws = (char*)d_ws;
    size_t off = 0;
    auto carve = [&](size_t bytes) {
        void* p = ws + off;
        off += (bytes + 255) & ~(size_t)255;
        return p;
    };
    __half*   Y1        = (__half*)carve((size_t)n * NG * 2);
    __half*   Y2        = (__half*)carve((size_t)n * NG * 2);
    __half*   Y3        = (__half*)carve((size_t)n * NG * 2);
    uint2*    euv       = (uint2*)carve((size_t)e * 8);
    float*    dinv      = (float*)carve((size_t)n * 4);
    unsigned* counts_src= (unsigned*)carve((size_t)n * 4);
    unsigned* row_start = (unsigned*)carve((size_t)(n + 1) * 4);
    unsigned* partials  = (unsigned*)carve(1024 * 4);
    int*      gstart    = (int*)carve(65 * 4);
    unsigned* wstart    = (unsigned*)carve((size_t)(VOC + 1) * 4);
    unsigned* sorted    = (unsigned*)carve((size_t)n * 4);
    float*    tapart    = (float*)carve((size_t)TAB * TAW * 4);   // 1.34 MB, plain stores
    // ---- zero region B ----
    char*     zB0       = (char*)carve(0);
    float*    su1       = (float*)carve((size_t)8 * NG * 4);
    float*    su2       = (float*)carve((size_t)8 * NG * 4);
    float*    ta        = (float*)carve((size_t)41 * NG * 4);
    float*    tw        = (float*)carve((size_t)KPAD * NG * 4);   // pad rows must be zero
    float*    G0        = (float*)carve((size_t)NG * 300 * 4);
    float*    r1        = (float*)carve(300 * 4);
    float*    r2        = (float*)carve(300 * 4);
    float*    T1        = (float*)carve((size_t)NG * 300 * 4);
    float*    T2        = (float*)carve((size_t)NG * 300 * 4);
    float*    T3        = (float*)carve((size_t)NG * 300 * 4);
    unsigned* wcnt      = (unsigned*)carve((size_t)VOC * 4);
    unsigned* wcur      = (unsigned*)carve((size_t)VOC * 4);
    char*     zB1       = (char*)carve(0);

    const int* src = ei;
    const int* dst = ei + e;

    // aliases (lifetime-disjoint):
    //  edge replicas in Y1/Y2 (dead before k_y1 writes Y1 / before yprop#1 writes Y2)
    //  Gpart (80*64*300*4 = 24.6MB) spans Y1+Y2 (both dead after yprop#2 reads Y2)
    unsigned* rep_in  = (unsigned*)Y1;
    unsigned* rep_src = (unsigned*)Y2;
    float*    Gpart   = (float*)Y1;

    hipMemsetAsync(zB0, 0, (size_t)(zB1 - zB0), stream);

    const int npairs = (n + 1) / 2;
    const int NRng   = (n + RSZ - 1) / RSZ;        // 8
    const int chunk  = (e + NC_MS - 1) / NC_MS;    // 12500

    // edge reverse-CSR (multi-split, no device atomics; 1024-thr blocks for occupancy)
    k_mscount<<<NRng * NC_MS, MSB, 0, stream>>>(src, dst, rep_in, rep_src, e, n, chunk, npairs);
    k_msreduce<<<(npairs + 255) / 256, 256, 0, stream>>>(rep_in, rep_src, dinv, counts_src, n, npairs);
    int NB = (n + 1023) / 1024;      // 98
    k_blocksum<<<NB, 256, 0, stream>>>(counts_src, partials, n);
    k_scanpartials<<<1, 128, 0, stream>>>(partials, NB);
    k_scanblock<<<NB, 256, 0, stream>>>(counts_src, partials, row_start, n);
    k_msfill<<<NRng * NC_MS, MSB, 0, stream>>>(src, dst, batch, row_start, rep_src, dinv, euv, e, n, chunk, npairs);
    k_gstart<<<1, 128, 0, stream>>>(batch, gstart, n, NGRAPH_C);

    // word counting sort (atomic cursor; order within word irrelevant)
    int nb256 = (n + 255) / 256;
    k_wcount<<<nb256, 256, 0, stream>>>(x, wcnt, n);
    int NBW = (VOC + 1023) / 1024;   // 10
    k_blocksum<<<NBW, 256, 0, stream>>>(wcnt, partials, VOC);
    k_scanpartials<<<1, 128, 0, stream>>>(partials, NBW);
    k_scanblock<<<NBW, 256, 0, stream>>>(wcnt, partials, wstart, VOC);
    k_wfill<<<nb256, 256, 0, stream>>>(x, wstart, wcur, sorted, n);

    // indicator propagation: Y1 -> Y2 -> Y3 (fp16)
    int yb = (n * 16 + 255) / 256;   // 6250
    k_y1<<<yb, 256, 0, stream>>>(batch, dinv, row_start, euv, Y1, n);
    k_colsumh<<<512, 256, 0, stream>>>(Y1, su1, n);
    k_yprop<<<yb, 256, 0, stream>>>(Y1, dinv, row_start, euv, Y2, n);
    k_colsumh<<<512, 256, 0, stream>>>(Y2, su2, n);
    k_yprop<<<yb, 256, 0, stream>>>(Y2, dinv, row_start, euv, Y3, n);

    // contractions -> G0 = Y3^T H0
    k_ta<<<TAB, 1024, 0, stream>>>(Y3, x, tapart, n);
    {
        dim3 gt((TAW + 255) / 256, 8);
        k_tareduce<<<gt, 256, 0, stream>>>(tapart, ta);
    }
    k_twfill<<<(VOC + 3) / 4, 256, 0, stream>>>(Y3, sorted, wstart, tw);
    {
        dim3 gw(5, NKC);   // 5 c-tiles x 80 k-chunks of 128
        k_wgemm2<<<gw, 256, 0, stream>>>(tw, wt, Gpart);
        dim3 gr((NG * 300 + 255) / 256, 8);
        k_greduce<<<gr, 256, 0, stream>>>(Gpart, G0);
    }
    k_agemm<<<(NG * 300 + 255) / 256, 256, 0, stream>>>(ta, at, G0);

    // W chain: T3 = G0 * W^3
    {
        dim3 gs((NG * 300 + 255) / 256, 5);
        k_smm<<<gs, 256, 0, stream>>>(G0, W, T1);
        k_smm<<<gs, 256, 0, stream>>>(T1, W, T2);
        k_smm<<<gs, 256, 0, stream>>>(T2, W, T3);
        dim3 gv(2, 4);
        k_vec<<<gv, 256, 0, stream>>>(b, W, r1);
        k_vec<<<gv, 256, 0, stream>>>(r1, W, r2);
    }

    k_out<<<(NG * 300 + 255) / 256, 256, 0, stream>>>(T3, su1, su2, gstart, r1, r2, b, (float*)d_out);
}

// Round 8
// 325.317 us; speedup vs baseline: 1.1341x; 1.1341x over previous
//
#include <hip/hip_runtime.h>
#include <hip/hip_fp16.h>

#define NG 64              // graphs (= Y feature width)
#define NGRAPH_C 64

// edge multi-split geometry
#define RSZ 12500          // nodes per range (8 ranges for n=100000)
#define RSZP 6250          // packed u16 pairs per range
#define NC_MS 64           // edge chunks
#define MSB 1024           // threads/block for count/fill (occupancy: 2 blk/CU x 16 waves)

// word contraction geometry
#define VOC 10000
#define KPAD 10240         // padded K for wgemm (80 chunks of 128)
#define NKC 80             // split-k chunks
#define WGK 128            // K per chunk

// atom sort geometry
#define NATOM 41
#define NC_A 128           // node chunks for atom sort
#define ASL 128            // gather slices per atom

// ---- bit casts ----
__device__ __forceinline__ unsigned f_as_u(float f) { union { float f; unsigned u; } c; c.f = f; return c.u; }
__device__ __forceinline__ float u_as_f(unsigned u) { union { unsigned u; float f; } c; c.u = u; return c.f; }

// XCD id (0..7)
__device__ __forceinline__ int xcc_id() {
    unsigned x;
    asm volatile("s_getreg_b32 %0, hwreg(HW_REG_XCC_ID)" : "=s"(x));
    return (int)(x & 7u);
}

union H4 { uint2 u2; __half h[4]; };

// ---------------- edge multi-split count (1024 thr) ----------------
__global__ __launch_bounds__(MSB) void k_mscount(const int* __restrict__ src, const int* __restrict__ dst,
                                                 unsigned* __restrict__ rep_in,
                                                 unsigned* __restrict__ rep_src,
                                                 int e, int n, int chunk, int npairs) {
    __shared__ unsigned hin[RSZP];
    __shared__ unsigned hsrc[RSZP];
    int c = blockIdx.x % NC_MS;
    int r = blockIdx.x / NC_MS;
    int base = r * RSZ;
    int t = threadIdx.x;
    for (int w = t; w < RSZP; w += MSB) { hin[w] = 0u; hsrc[w] = 0u; }
    __syncthreads();
    int e0 = c * chunk, e1 = min(e, e0 + chunk);
    for (int i = e0 + t; i < e1; i += MSB) {
        int s = src[i], d = dst[i];
        unsigned ud = (unsigned)(d - base);
        unsigned us = (unsigned)(s - base);
        if (ud < (unsigned)RSZ) atomicAdd(&hin[ud >> 1], 1u << ((ud & 1) * 16));
        if (us < (unsigned)RSZ) atomicAdd(&hsrc[us >> 1], 1u << ((us & 1) * 16));
    }
    __syncthreads();
    int lim = min(RSZ, n - base);
    if (lim <= 0) return;
    int plim = (lim + 1) >> 1;
    unsigned* gin  = rep_in  + (size_t)c * npairs + (base >> 1);
    unsigned* gsrc = rep_src + (size_t)c * npairs + (base >> 1);
    for (int w = t; w < plim; w += MSB) { gin[w] = hin[w]; gsrc[w] = hsrc[w]; }
}

__global__ __launch_bounds__(256) void k_msreduce(const unsigned* __restrict__ rep_in,
                                                  unsigned* __restrict__ rep_src,   // -> pref
                                                  float* __restrict__ dinv,
                                                  unsigned* __restrict__ counts_src,
                                                  int n, int npairs) {
    int i2 = blockIdx.x * 256 + threadIdx.x;
    if (i2 >= npairs) return;
    unsigned slo = 0, shi = 0, rlo = 0, rhi = 0;
#pragma unroll 4
    for (int c = 0; c < NC_MS; ++c) {
        unsigned vi = rep_in[(size_t)c * npairs + i2];
        slo += vi & 0xFFFFu; shi += vi >> 16;
        unsigned vs = rep_src[(size_t)c * npairs + i2];
        rep_src[(size_t)c * npairs + i2] = rlo | (rhi << 16);
        rlo += vs & 0xFFFFu; rhi += vs >> 16;
    }
    int i = i2 * 2;
    dinv[i] = rsqrtf((float)(slo + 1u));
    counts_src[i] = rlo;
    if (i + 1 < n) {
        dinv[i + 1] = rsqrtf((float)(shi + 1u));
        counts_src[i + 1] = rhi;
    }
}

// ---------------- 2-level exclusive scan ----------------
__global__ __launch_bounds__(256) void k_blocksum(const unsigned* __restrict__ counts,
                                                  unsigned* __restrict__ partials, int n) {
    __shared__ unsigned s[256];
    int base = blockIdx.x * 1024;
    unsigned sum = 0;
    for (int j = threadIdx.x; j < 1024; j += 256) {
        int i = base + j;
        sum += (i < n) ? counts[i] : 0u;
    }
    s[threadIdx.x] = sum;
    __syncthreads();
    for (int off = 128; off > 0; off >>= 1) {
        if (threadIdx.x < (unsigned)off) s[threadIdx.x] += s[threadIdx.x + off];
        __syncthreads();
    }
    if (threadIdx.x == 0) partials[blockIdx.x] = s[0];
}

__global__ __launch_bounds__(128) void k_scanpartials(unsigned* __restrict__ partials, int nb) {
    __shared__ unsigned s[128];
    int t = threadIdx.x;
    s[t] = (t < nb) ? partials[t] : 0u;
    __syncthreads();
    if (t == 0) {
        unsigned run = 0;
        for (int i = 0; i < nb; ++i) { unsigned v = s[i]; s[i] = run; run += v; }
    }
    __syncthreads();
    if (t < nb) partials[t] = s[t];
}

__global__ __launch_bounds__(256) void k_scanblock(const unsigned* __restrict__ counts,
                                                   const unsigned* __restrict__ partials,
                                                   unsigned* __restrict__ row_start, int n) {
    __shared__ unsigned s[256];
    int base = blockIdx.x * 1024;
    int t = threadIdx.x;
    unsigned v[4];
    unsigned tsum = 0;
#pragma unroll
    for (int j = 0; j < 4; ++j) {
        int i = base + t * 4 + j;
        v[j] = (i < n) ? counts[i] : 0u;
        tsum += v[j];
    }
    s[t] = tsum;
    __syncthreads();
    for (int off = 1; off < 256; off <<= 1) {
        unsigned x = (t >= off) ? s[t - off] : 0u;
        __syncthreads();
        s[t] += x;
        __syncthreads();
    }
    unsigned excl = (t > 0 ? s[t - 1] : 0u) + partials[blockIdx.x];
#pragma unroll
    for (int j = 0; j < 4; ++j) {
        int i = base + t * 4 + j;
        if (i < n) {
            row_start[i] = excl;
            excl += v[j];
            if (i == n - 1) row_start[n] = excl;
        }
    }
}

// ---------------- edge multi-split fill (1024 thr) ----------------
__global__ __launch_bounds__(MSB) void k_msfill(const int* __restrict__ src, const int* __restrict__ dst,
                                                const int* __restrict__ batch,
                                                const unsigned* __restrict__ row_start,
                                                const unsigned* __restrict__ pref,
                                                const float* __restrict__ dinv,
                                                uint2* __restrict__ euv,
                                                int e, int n, int chunk, int npairs) {
    __shared__ unsigned cur[RSZP];
    int c = blockIdx.x % NC_MS;
    int r = blockIdx.x / NC_MS;
    int base = r * RSZ;
    int t = threadIdx.x;
    for (int w = t; w < RSZP; w += MSB) cur[w] = 0u;
    __syncthreads();
    int e0 = c * chunk, e1 = min(e, e0 + chunk);
    const unsigned* prefc = pref + (size_t)c * npairs;
    for (int i = e0 + t; i < e1; i += MSB) {
        int s = src[i];
        unsigned us = (unsigned)(s - base);
        if (us < (unsigned)RSZ) {
            int d = dst[i];
            unsigned sh = (us & 1) * 16;
            unsigned old = atomicAdd(&cur[us >> 1], 1u << sh);
            unsigned slot = (old >> sh) & 0xFFFFu;
            unsigned p16 = (prefc[(unsigned)s >> 1] >> ((s & 1) * 16)) & 0xFFFFu;
            unsigned pos = row_start[s] + p16 + slot;
            uint2 pv;
            pv.x = (unsigned)d | ((unsigned)batch[d] << 17);
            pv.y = f_as_u(dinv[s] * dinv[d]);
            euv[pos] = pv;
        }
    }
}

// ---------------- word counting sort (order-free: atomic cursor) ----------------
__global__ __launch_bounds__(256) void k_wcount(const int* __restrict__ x,
                                                unsigned* __restrict__ wcnt, int n) {
    int j = blockIdx.x * 256 + threadIdx.x;
    if (j >= n) return;
    atomicAdd(&wcnt[x[2 * j + 1]], 1u);
}

__global__ __launch_bounds__(256) void k_wfill(const int* __restrict__ x,
                                               const unsigned* __restrict__ wstart,
                                               unsigned* __restrict__ wcur,
                                               unsigned* __restrict__ sorted, int n) {
    int j = blockIdx.x * 256 + threadIdx.x;
    if (j >= n) return;
    int w = x[2 * j + 1];
    unsigned pos = wstart[w] + atomicAdd(&wcur[w], 1u);
    sorted[pos] = (unsigned)j;
}

// ---------------- per-word column sums: tw[w][g] (plain stores) ----------------
__global__ __launch_bounds__(256) void k_twfill(const __half* __restrict__ Y3,
                                                const unsigned* __restrict__ sorted,
                                                const unsigned* __restrict__ wstart,
                                                float* __restrict__ tw) {
    int w = blockIdx.x * 4 + (threadIdx.x >> 6);
    int g = threadIdx.x & 63;
    if (w >= VOC) return;
    unsigned i0 = wstart[w], i1 = wstart[w + 1];
    float s = 0.f;
    unsigned i = i0;
    for (; i + 2 <= i1; i += 2) {
        unsigned j0 = sorted[i], j1 = sorted[i + 1];
        s += __half2float(Y3[(size_t)j0 * NG + g]) + __half2float(Y3[(size_t)j1 * NG + g]);
    }
    if (i < i1) {
        unsigned j0 = sorted[i];
        s += __half2float(Y3[(size_t)j0 * NG + g]);
    }
    tw[(size_t)w * NG + g] = s;
}

// ---------------- atom counting sort: LDS-hist multi-split (no device atomics) ----------------
__global__ __launch_bounds__(256) void k_amscount(const int* __restrict__ x,
                                                  unsigned* __restrict__ rep_a,
                                                  int n, int chunk) {
    __shared__ unsigned h[NATOM];
    int c = blockIdx.x;
    int t = threadIdx.x;
    if (t < NATOM) h[t] = 0u;
    __syncthreads();
    int j0 = c * chunk, j1 = min(n, j0 + chunk);
    for (int j = j0 + t; j < j1; j += 256) atomicAdd(&h[x[2 * j]], 1u);
    __syncthreads();
    if (t < NATOM) rep_a[c * NATOM + t] = h[t];
}

// single block: per-chunk exclusive prefixes (in place) + astart
__global__ __launch_bounds__(64) void k_amsscan(unsigned* __restrict__ rep_a,
                                                unsigned* __restrict__ astart, int n) {
    __shared__ unsigned tot[NATOM];
    int t = threadIdx.x;
    if (t < NATOM) {
        unsigned run = 0;
        for (int c = 0; c < NC_A; ++c) {
            unsigned v = rep_a[c * NATOM + t];
            rep_a[c * NATOM + t] = run;
            run += v;
        }
        tot[t] = run;
    }
    __syncthreads();
    if (t == 0) {
        unsigned run = 0;
        for (int a = 0; a < NATOM; ++a) { astart[a] = run; run += tot[a]; }
        astart[NATOM] = run;   // == n
    }
}

__global__ __launch_bounds__(256) void k_amsfill(const int* __restrict__ x,
                                                 const unsigned* __restrict__ astart,
                                                 const unsigned* __restrict__ rep_a,
                                                 unsigned* __restrict__ asorted,
                                                 int n, int chunk) {
    __shared__ unsigned cur[NATOM];
    __shared__ unsigned base[NATOM];
    int c = blockIdx.x;
    int t = threadIdx.x;
    if (t < NATOM) {
        cur[t] = 0u;
        base[t] = astart[t] + rep_a[c * NATOM + t];
    }
    __syncthreads();
    int j0 = c * chunk, j1 = min(n, j0 + chunk);
    for (int j = j0 + t; j < j1; j += 256) {
        int a = x[2 * j];
        unsigned slot = atomicAdd(&cur[a], 1u);
        asorted[base[a] + slot] = (unsigned)j;
    }
}

// ---------------- atom gather: register sums, plain-store partials ----------------
// 41 atoms x ASL slices, wave per slice; twfill-proven shape (no LDS atomics).
__global__ __launch_bounds__(256) void k_tafill(const __half* __restrict__ Y3,
                                                const unsigned* __restrict__ asorted,
                                                const unsigned* __restrict__ astart,
                                                float* __restrict__ tap) {
    int wid = blockIdx.x * 4 + (threadIdx.x >> 6);
    if (wid >= NATOM * ASL) return;
    int a  = wid >> 7;            // / ASL
    int sl = wid & (ASL - 1);
    int g  = threadIdx.x & 63;
    unsigned i0 = astart[a], i1 = astart[a + 1];
    unsigned len = i1 - i0;
    unsigned lo = i0 + (unsigned)((unsigned long long)len * sl / ASL);
    unsigned hi = i0 + (unsigned)((unsigned long long)len * (sl + 1) / ASL);
    float s = 0.f;
    unsigned i = lo;
    for (; i + 2 <= hi; i += 2) {
        unsigned j0 = asorted[i], j1 = asorted[i + 1];
        s += __half2float(Y3[(size_t)j0 * NG + g]) + __half2float(Y3[(size_t)j1 * NG + g]);
    }
    if (i < hi) s += __half2float(Y3[(size_t)asorted[i] * NG + g]);
    tap[((size_t)a * ASL + sl) * NG + g] = s;
}

// ta[a][g] = sum over slices (plain store, coalesced per iteration)
__global__ __launch_bounds__(256) void k_tareduce(const float* __restrict__ tap,
                                                  float* __restrict__ ta) {
    int i = blockIdx.x * 256 + threadIdx.x;
    if (i >= NATOM * NG) return;
    int a = i >> 6;
    int g = i & 63;
    float s = 0.f;
    for (int sl = 0; sl < ASL; ++sl) s += tap[((size_t)a * ASL + sl) * NG + g];
    ta[i] = s;
}

// ---------------- graph boundaries (batch sorted) ----------------
__global__ __launch_bounds__(128) void k_gstart(const int* __restrict__ batch,
                                                int* __restrict__ gstart, int n, int ngraph) {
    int g = threadIdx.x;
    if (g > ngraph) return;
    if (g == ngraph) { gstart[g] = n; return; }
    int lo = 0, hi = n;
    while (lo < hi) {
        int mid = (lo + hi) >> 1;
        if (batch[mid] < g) lo = mid + 1; else hi = mid;
    }
    gstart[g] = lo;
}

// ---------------- hop 1 (fp16 out, 4-wide unrolled edge loop) ----------------
__global__ __launch_bounds__(256) void k_y1(const int* __restrict__ batch,
                                            const float* __restrict__ dinv,
                                            const unsigned* __restrict__ row_start,
                                            const uint2* __restrict__ euv,
                                            __half* __restrict__ Y1, int n) {
    int idx = blockIdx.x * 256 + threadIdx.x;
    if (idx >= n * 16) return;
    int j = idx >> 4;
    int c4 = idx & 15;
    int cb = c4 * 4;
    float a0 = 0.f, a1 = 0.f, a2 = 0.f, a3 = 0.f;
    {
        int bj = batch[j];
        float dj = dinv[j];
        float sn = dj * dj;
        a0 += (bj == cb + 0) ? sn : 0.f;
        a1 += (bj == cb + 1) ? sn : 0.f;
        a2 += (bj == cb + 2) ? sn : 0.f;
        a3 += (bj == cb + 3) ? sn : 0.f;
    }
    unsigned e0 = row_start[j], e1 = row_start[j + 1];
    unsigned e = e0;
    for (; e + 4 <= e1; e += 4) {
        uint2 p0 = euv[e], p1 = euv[e + 1], p2 = euv[e + 2], p3 = euv[e + 3];
        int b0 = (int)(p0.x >> 17), b1 = (int)(p1.x >> 17);
        int b2 = (int)(p2.x >> 17), b3 = (int)(p3.x >> 17);
        float v0 = u_as_f(p0.y), v1 = u_as_f(p1.y);
        float v2 = u_as_f(p2.y), v3 = u_as_f(p3.y);
        a0 += ((b0 == cb + 0) ? v0 : 0.f) + ((b1 == cb + 0) ? v1 : 0.f)
            + ((b2 == cb + 0) ? v2 : 0.f) + ((b3 == cb + 0) ? v3 : 0.f);
        a1 += ((b0 == cb + 1) ? v0 : 0.f) + ((b1 == cb + 1) ? v1 : 0.f)
            + ((b2 == cb + 1) ? v2 : 0.f) + ((b3 == cb + 1) ? v3 : 0.f);
        a2 += ((b0 == cb + 2) ? v0 : 0.f) + ((b1 == cb + 2) ? v1 : 0.f)
            + ((b2 == cb + 2) ? v2 : 0.f) + ((b3 == cb + 2) ? v3 : 0.f);
        a3 += ((b0 == cb + 3) ? v0 : 0.f) + ((b1 == cb + 3) ? v1 : 0.f)
            + ((b2 == cb + 3) ? v2 : 0.f) + ((b3 == cb + 3) ? v3 : 0.f);
    }
    for (; e < e1; ++e) {
        uint2 p = euv[e];
        int bd = (int)(p.x >> 17);
        float v = u_as_f(p.y);
        a0 += (bd == cb + 0) ? v : 0.f;
        a1 += (bd == cb + 1) ? v : 0.f;
        a2 += (bd == cb + 2) ? v : 0.f;
        a3 += (bd == cb + 3) ? v : 0.f;
    }
    H4 o;
    o.h[0] = __float2half(a0); o.h[1] = __float2half(a1);
    o.h[2] = __float2half(a2); o.h[3] = __float2half(a3);
    *(uint2*)&Y1[(size_t)j * NG + cb] = o.u2;
}

// ---------------- Y-hop fp16 -> fp16 (4-wide unrolled gather for MLP) ----------------
__global__ __launch_bounds__(256) void k_yprop(const __half* __restrict__ Yin,
                                               const float* __restrict__ dinv,
                                               const unsigned* __restrict__ row_start,
                                               const uint2* __restrict__ euv,
                                               __half* __restrict__ Yout, int n) {
    int idx = blockIdx.x * 256 + threadIdx.x;
    if (idx >= n * 16) return;
    int j = idx >> 4;
    int c4 = idx & 15;
    int cb = c4 * 4;
    float dj = dinv[j];
    float sn = dj * dj;
    H4 s; s.u2 = *(const uint2*)&Yin[(size_t)j * NG + cb];
    float a0 = sn * __half2float(s.h[0]);
    float a1 = sn * __half2float(s.h[1]);
    float a2 = sn * __half2float(s.h[2]);
    float a3 = sn * __half2float(s.h[3]);
    unsigned e0 = row_start[j], e1 = row_start[j + 1];
    unsigned e = e0;
    for (; e + 4 <= e1; e += 4) {
        uint2 p0 = euv[e], p1 = euv[e + 1], p2 = euv[e + 2], p3 = euv[e + 3];
        float v0 = u_as_f(p0.y), v1 = u_as_f(p1.y);
        float v2 = u_as_f(p2.y), v3 = u_as_f(p3.y);
        H4 m0; m0.u2 = *(const uint2*)&Yin[(size_t)(p0.x & 0x1FFFFu) * NG + cb];
        H4 m1; m1.u2 = *(const uint2*)&Yin[(size_t)(p1.x & 0x1FFFFu) * NG + cb];
        H4 m2; m2.u2 = *(const uint2*)&Yin[(size_t)(p2.x & 0x1FFFFu) * NG + cb];
        H4 m3; m3.u2 = *(const uint2*)&Yin[(size_t)(p3.x & 0x1FFFFu) * NG + cb];
        a0 += v0 * __half2float(m0.h[0]) + v1 * __half2float(m1.h[0])
            + v2 * __half2float(m2.h[0]) + v3 * __half2float(m3.h[0]);
        a1 += v0 * __half2float(m0.h[1]) + v1 * __half2float(m1.h[1])
            + v2 * __half2float(m2.h[1]) + v3 * __half2float(m3.h[1]);
        a2 += v0 * __half2float(m0.h[2]) + v1 * __half2float(m1.h[2])
            + v2 * __half2float(m2.h[2]) + v3 * __half2float(m3.h[2]);
        a3 += v0 * __half2float(m0.h[3]) + v1 * __half2float(m1.h[3])
            + v2 * __half2float(m2.h[3]) + v3 * __half2float(m3.h[3]);
    }
    for (; e < e1; ++e) {
        uint2 p0 = euv[e];
        float v0 = u_as_f(p0.y);
        H4 m0; m0.u2 = *(const uint2*)&Yin[(size_t)(p0.x & 0x1FFFFu) * NG + cb];
        a0 += v0 * __half2float(m0.h[0]);
        a1 += v0 * __half2float(m0.h[1]);
        a2 += v0 * __half2float(m0.h[2]);
        a3 += v0 * __half2float(m0.h[3]);
    }
    H4 o;
    o.h[0] = __float2half(a0); o.h[1] = __float2half(a1);
    o.h[2] = __float2half(a2); o.h[3] = __float2half(a3);
    *(uint2*)&Yout[(size_t)j * NG + cb] = o.u2;
}

// ---------------- column sums (fp16 input), XCC-replicated output ----------------
__global__ __launch_bounds__(256) void k_colsumh(const __half* __restrict__ Y,
                                                 float* __restrict__ su8, int n) {
    __shared__ float red[16][NG];
    int t = threadIdx.x;
    int cg = t & 15;
    int sr = t >> 4;
    float a0 = 0.f, a1 = 0.f, a2 = 0.f, a3 = 0.f;
    int stride = gridDim.x * 16;
    for (int j = blockIdx.x * 16 + sr; j < n; j += stride) {
        H4 v; v.u2 = *(const uint2*)&Y[(size_t)j * NG + cg * 4];
        a0 += __half2float(v.h[0]);
        a1 += __half2float(v.h[1]);
        a2 += __half2float(v.h[2]);
        a3 += __half2float(v.h[3]);
    }
    red[sr][cg * 4 + 0] = a0;
    red[sr][cg * 4 + 1] = a1;
    red[sr][cg * 4 + 2] = a2;
    red[sr][cg * 4 + 3] = a3;
    __syncthreads();
    if (t < NG) {
        float s = 0.f;
#pragma unroll
        for (int q = 0; q < 16; ++q) s += red[q][t];
        int r = xcc_id();
        __hip_atomic_fetch_add(&su8[r * NG + t], s,
                               __ATOMIC_RELAXED, __HIP_MEMORY_SCOPE_WORKGROUP);
    }
}

// ---------------- tiled word contraction: Gpart[kc] = tw_chunk^T @ wt_chunk ----------------
__global__ __launch_bounds__(256) void k_wgemm2(const float* __restrict__ T,    // [KPAD][64]
                                                const float* __restrict__ Tab,  // [10000][300]
                                                float* __restrict__ Gpart) {
    __shared__ float Asm[32 * 64];
    __shared__ float Bsm[32 * 64];
    const int t = threadIdx.x;
    const int tg = t >> 4;
    const int tc = t & 15;
    const int c0 = blockIdx.x * 64;
    const int kb = blockIdx.y * WGK;

    float acc[4][4] = {};

    for (int sub = 0; sub < WGK / 32; ++sub) {
        int kbase = kb + sub * 32;
#pragma unroll
        for (int r2 = 0; r2 < 2; ++r2) {
            int idx4 = r2 * 256 + t;
            int k = idx4 >> 4, g4 = idx4 & 15;
            float4 v = *(const float4*)&T[(size_t)(kbase + k) * 64 + g4 * 4];
            *(float4*)&Asm[k * 64 + g4 * 4] = v;
        }
#pragma unroll
        for (int r2 = 0; r2 < 2; ++r2) {
            int idx4 = r2 * 256 + t;
            int k = idx4 >> 4, c4i = idx4 & 15;
            int gk = kbase + k;
            int cb2 = c0 + c4i * 4;
            float4 v;
            if (gk < VOC && cb2 + 3 < 300) {
                v = *(const float4*)&Tab[(size_t)gk * 300 + cb2];
            } else {
                float tmp[4];
#pragma unroll
                for (int q = 0; q < 4; ++q)
                    tmp[q] = (gk < VOC && cb2 + q < 300) ? Tab[(size_t)gk * 300 + cb2 + q] : 0.f;
                v.x = tmp[0]; v.y = tmp[1]; v.z = tmp[2]; v.w = tmp[3];
            }
            *(float4*)&Bsm[k * 64 + c4i * 4] = v;
        }
        __syncthreads();
#pragma unroll 8
        for (int k = 0; k < 32; ++k) {
            float4 a4 = *(const float4*)&Asm[k * 64 + tg * 4];
            float4 b4 = *(const float4*)&Bsm[k * 64 + tc * 4];
            float a[4] = {a4.x, a4.y, a4.z, a4.w};
            float b[4] = {b4.x, b4.y, b4.z, b4.w};
#pragma unroll
            for (int i = 0; i < 4; ++i)
#pragma unroll
                for (int jj = 0; jj < 4; ++jj) acc[i][jj] += a[i] * b[jj];
        }
        __syncthreads();
    }

    float* gp = Gpart + (size_t)blockIdx.y * (NG * 300);
#pragma unroll
    for (int i = 0; i < 4; ++i) {
        int g = tg * 4 + i;
#pragma unroll
        for (int jj = 0; jj < 4; ++jj) {
            int c = c0 + tc * 4 + jj;
            if (c < 300) gp[g * 300 + c] = acc[i][jj];
        }
    }
}

// reduce k-chunk partials into G0 (few atomics; G0 zeroed)
__global__ __launch_bounds__(256) void k_greduce(const float* __restrict__ Gpart,
                                                 float* __restrict__ G0) {
    int k = blockIdx.x * 256 + threadIdx.x;
    if (k >= NG * 300) return;
    int p0 = blockIdx.y * (NKC / 8);
    int p1 = p0 + (NKC / 8);
    float s = 0.f;
    for (int p = p0; p < p1; ++p) s += Gpart[(size_t)p * (NG * 300) + k];
    atomicAdd(&G0[k], s);
}

// ---------------- atom contraction: K=41 ----------------
__global__ __launch_bounds__(256) void k_agemm(const float* __restrict__ T,
                                               const float* __restrict__ Tab,
                                               float* __restrict__ G0) {
    int j = blockIdx.x * 256 + threadIdx.x;
    if (j >= NG * 300) return;
    int g = j / 300, c = j - g * 300;
    float acc = 0.f;
#pragma unroll
    for (int k = 0; k < 41; ++k) acc += T[(size_t)k * NG + g] * Tab[(size_t)k * 300 + c];
    atomicAdd(&G0[j], acc);
}

// ---------------- small GEMM split-k ----------------
__global__ __launch_bounds__(256) void k_smm(const float* __restrict__ A,
                                             const float* __restrict__ W,
                                             float* __restrict__ C) {
    int j = blockIdx.x * 256 + threadIdx.x;
    if (j >= NG * 300) return;
    int g = j / 300, c = j - g * 300;
    int k0 = blockIdx.y * 60;
    float acc = 0.f;
#pragma unroll 1
    for (int k = k0; k < k0 + 60; k += 4) {
        float a0 = A[g * 300 + k + 0], a1 = A[g * 300 + k + 1];
        float a2 = A[g * 300 + k + 2], a3 = A[g * 300 + k + 3];
        float w0 = W[(k + 0) * 300 + c], w1 = W[(k + 1) * 300 + c];
        float w2 = W[(k + 2) * 300 + c], w3 = W[(k + 3) * 300 + c];
        acc += a0 * w0 + a1 * w1 + a2 * w2 + a3 * w3;
    }
    atomicAdd(&C[j], acc);
}

// ---------------- vector-matrix ----------------
__global__ __launch_bounds__(256) void k_vec(const float* __restrict__ vin,
                                             const float* __restrict__ W,
                                             float* __restrict__ r_out) {
    int c = blockIdx.x * 256 + threadIdx.x;
    if (c >= 300) return;
    int k0 = blockIdx.y * 75;
    float acc = 0.f;
    for (int k = k0; k < k0 + 75; ++k) acc += vin[k] * W[k * 300 + c];
    atomicAdd(&r_out[c], acc);
}

// ---------------- final assembly ----------------
__global__ __launch_bounds__(256) void k_out(const float* __restrict__ T3,
                                             const float* __restrict__ su1,
                                             const float* __restrict__ su2,
                                             const int* __restrict__ gstart,
                                             const float* __restrict__ r1,
                                             const float* __restrict__ r2,
                                             const float* __restrict__ b,
                                             float* __restrict__ out) {
    int j = blockIdx.x * 256 + threadIdx.x;
    if (j >= NG * 300) return;
    int g = j / 300, c = j - g * 300;
    int cnt = gstart[g + 1] - gstart[g];
    float s1 = 0.f, s2 = 0.f;
#pragma unroll
    for (int r = 0; r < 8; ++r) {
        s1 += su1[r * NG + g];
        s2 += su2[r * NG + g];
    }
    float v = T3[j] + s2 * r2[c] + s1 * r1[c] + (float)cnt * b[c];
    out[j] = v / (float)(cnt > 0 ? cnt : 1);
}

// ---------------- launch ----------------
extern "C" void kernel_launch(void* const* d_in, const int* in_sizes, int n_in,
                              void* d_out, int out_size, void* d_ws, size_t ws_size,
                              hipStream_t stream) {
    const int*   x     = (const int*)d_in[0];
    const int*   ei    = (const int*)d_in[1];
    const int*   batch = (const int*)d_in[2];
    const float* at    = (const float*)d_in[3];
    const float* wt    = (const float*)d_in[4];
    const float* W     = (const float*)d_in[5];
    const float* b     = (const float*)d_in[6];

    const int n = in_sizes[0] / 2;   // 100000
    const int e = in_sizes[1] / 2;   // 800000

    char* ws = (char*)d_ws;
    size_t off = 0;
    auto carve = [&](size_t bytes) {
        void* p = ws + off;
        off += (bytes + 255) & ~(size_t)255;
        return p;
    };
    __half*   Y1        = (__half*)carve((size_t)n * NG * 2);
    __half*   Y2        = (__half*)carve((size_t)n * NG * 2);
    __half*   Y3        = (__half*)carve((size_t)n * NG * 2);
    uint2*    euv       = (uint2*)carve((size_t)e * 8);
    float*    dinv      = (float*)carve((size_t)n * 4);
    unsigned* counts_src= (unsigned*)carve((size_t)n * 4);
    unsigned* row_start = (unsigned*)carve((size_t)(n + 1) * 4);
    unsigned* partials  = (unsigned*)carve(1024 * 4);
    int*      gstart    = (int*)carve(65 * 4);
    unsigned* wstart    = (unsigned*)carve((size_t)(VOC + 1) * 4);
    unsigned* sorted    = (unsigned*)carve((size_t)n * 4);
    unsigned* asorted   = (unsigned*)carve((size_t)n * 4);
    unsigned* astart    = (unsigned*)carve((NATOM + 1) * 4);
    unsigned* rep_a     = (unsigned*)carve((size_t)NC_A * NATOM * 4);
    float*    tap       = (float*)carve((size_t)NATOM * ASL * NG * 4);  // 1.34 MB
    // ---- zero region B ----
    char*     zB0       = (char*)carve(0);
    float*    su1       = (float*)carve((size_t)8 * NG * 4);
    float*    su2       = (float*)carve((size_t)8 * NG * 4);
    float*    ta        = (float*)carve((size_t)NATOM * NG * 4);
    float*    tw        = (float*)carve((size_t)KPAD * NG * 4);   // pad rows must be zero
    float*    G0        = (float*)carve((size_t)NG * 300 * 4);
    float*    r1        = (float*)carve(300 * 4);
    float*    r2        = (float*)carve(300 * 4);
    float*    T1        = (float*)carve((size_t)NG * 300 * 4);
    float*    T2        = (float*)carve((size_t)NG * 300 * 4);
    float*    T3        = (float*)carve((size_t)NG * 300 * 4);
    unsigned* wcnt      = (unsigned*)carve((size_t)VOC * 4);
    unsigned* wcur      = (unsigned*)carve((size_t)VOC * 4);
    char*     zB1       = (char*)carve(0);

    const int* src = ei;
    const int* dst = ei + e;

    // aliases (lifetime-disjoint):
    //  edge replicas in Y1/Y2 (dead before k_y1 writes Y1 / before yprop#1 writes Y2)
    //  Gpart (80*64*300*4 = 24.6MB) spans Y1+Y2 (both dead after yprop#2 reads Y2)
    unsigned* rep_in  = (unsigned*)Y1;
    unsigned* rep_src = (unsigned*)Y2;
    float*    Gpart   = (float*)Y1;

    hipMemsetAsync(zB0, 0, (size_t)(zB1 - zB0), stream);

    const int npairs = (n + 1) / 2;
    const int NRng   = (n + RSZ - 1) / RSZ;        // 8
    const int chunk  = (e + NC_MS - 1) / NC_MS;    // 12500
    const int achunk = (n + NC_A - 1) / NC_A;      // 782

    // edge reverse-CSR (multi-split, no device atomics; 1024-thr blocks for occupancy)
    k_mscount<<<NRng * NC_MS, MSB, 0, stream>>>(src, dst, rep_in, rep_src, e, n, chunk, npairs);
    k_msreduce<<<(npairs + 255) / 256, 256, 0, stream>>>(rep_in, rep_src, dinv, counts_src, n, npairs);
    int NB = (n + 1023) / 1024;      // 98
    k_blocksum<<<NB, 256, 0, stream>>>(counts_src, partials, n);
    k_scanpartials<<<1, 128, 0, stream>>>(partials, NB);
    k_scanblock<<<NB, 256, 0, stream>>>(counts_src, partials, row_start, n);
    k_msfill<<<NRng * NC_MS, MSB, 0, stream>>>(src, dst, batch, row_start, rep_src, dinv, euv, e, n, chunk, npairs);
    k_gstart<<<1, 128, 0, stream>>>(batch, gstart, n, NGRAPH_C);

    // word counting sort (atomic cursor; order within word irrelevant)
    int nb256 = (n + 255) / 256;
    k_wcount<<<nb256, 256, 0, stream>>>(x, wcnt, n);
    int NBW = (VOC + 1023) / 1024;   // 10
    k_blocksum<<<NBW, 256, 0, stream>>>(wcnt, partials, VOC);
    k_scanpartials<<<1, 128, 0, stream>>>(partials, NBW);
    k_scanblock<<<NBW, 256, 0, stream>>>(wcnt, partials, wstart, VOC);
    k_wfill<<<nb256, 256, 0, stream>>>(x, wstart, wcur, sorted, n);

    // atom counting sort (LDS-hist multi-split, no device atomics)
    k_amscount<<<NC_A, 256, 0, stream>>>(x, rep_a, n, achunk);
    k_amsscan<<<1, 64, 0, stream>>>(rep_a, astart, n);
    k_amsfill<<<NC_A, 256, 0, stream>>>(x, astart, rep_a, asorted, n, achunk);

    // indicator propagation: Y1 -> Y2 -> Y3 (fp16)
    int yb = (n * 16 + 255) / 256;   // 6250
    k_y1<<<yb, 256, 0, stream>>>(batch, dinv, row_start, euv, Y1, n);
    k_colsumh<<<512, 256, 0, stream>>>(Y1, su1, n);
    k_yprop<<<yb, 256, 0, stream>>>(Y1, dinv, row_start, euv, Y2, n);
    k_colsumh<<<512, 256, 0, stream>>>(Y2, su2, n);
    k_yprop<<<yb, 256, 0, stream>>>(Y2, dinv, row_start, euv, Y3, n);

    // contractions -> G0 = Y3^T H0
    k_tafill<<<(NATOM * ASL + 3) / 4, 256, 0, stream>>>(Y3, asorted, astart, tap);
    k_tareduce<<<(NATOM * NG + 255) / 256, 256, 0, stream>>>(tap, ta);
    k_twfill<<<(VOC + 3) / 4, 256, 0, stream>>>(Y3, sorted, wstart, tw);
    {
        dim3 gw(5, NKC);   // 5 c-tiles x 80 k-chunks of 128
        k_wgemm2<<<gw, 256, 0, stream>>>(tw, wt, Gpart);
        dim3 gr((NG * 300 + 255) / 256, 8);
        k_greduce<<<gr, 256, 0, stream>>>(Gpart, G0);
    }
    k_agemm<<<(NG * 300 + 255) / 256, 256, 0, stream>>>(ta, at, G0);

    // W chain: T3 = G0 * W^3
    {
        dim3 gs((NG * 300 + 255) / 256, 5);
        k_smm<<<gs, 256, 0, stream>>>(G0, W, T1);
        k_smm<<<gs, 256, 0, stream>>>(T1, W, T2);
        k_smm<<<gs, 256, 0, stream>>>(T2, W, T3);
        dim3 gv(2, 4);
        k_vec<<<gv, 256, 0, stream>>>(b, W, r1);
        k_vec<<<gv, 256, 0, stream>>>(r1, W, r2);
    }

    k_out<<<(NG * 300 + 255) / 256, 256, 0, stream>>>(T3, su1, su2, gstart, r1, r2, b, (float*)d_out);
}

// Round 9
// 325.092 us; speedup vs baseline: 1.1348x; 1.0007x over previous
//
#include <hip/hip_runtime.h>
#include <hip/hip_fp16.h>

#define NG 64              // graphs (= Y feature width)
#define NGRAPH_C 64

// edge multi-split geometry (u8-packed LDS histograms)
#define RSZ 25000          // nodes per range (4 ranges for n=100000)
#define RSZP4 6250         // packed u8 quads per range
#define NC_MS 128          // edge chunks
#define NRNG 4
#define MSB 1024           // threads/block (2 blk/CU x 16 waves)

// word contraction geometry
#define VOC 10000
#define KPAD 10240         // padded K for wgemm (160 chunks of 64)
#define NKC 160            // split-k chunks
#define WGK 64             // K per chunk

// atom sort geometry
#define NATOM 41
#define NC_A 128           // node chunks for atom sort
#define ASL 128            // gather slices per atom

// ---- bit casts ----
__device__ __forceinline__ unsigned f_as_u(float f) { union { float f; unsigned u; } c; c.f = f; return c.u; }
__device__ __forceinline__ float u_as_f(unsigned u) { union { unsigned u; float f; } c; c.u = u; return c.f; }

// XCD id (0..7)
__device__ __forceinline__ int xcc_id() {
    unsigned x;
    asm volatile("s_getreg_b32 %0, hwreg(HW_REG_XCC_ID)" : "=s"(x));
    return (int)(x & 7u);
}

union H4 { uint2 u2; __half h[4]; };

// ---------------- edge multi-split count (u8 LDS hist; per-chunk counts << 255) ----------------
__global__ __launch_bounds__(MSB) void k_mscount(const int* __restrict__ src, const int* __restrict__ dst,
                                                 unsigned* __restrict__ rep_in,
                                                 unsigned* __restrict__ rep_src,
                                                 int e, int n, int chunk, int nwords) {
    __shared__ unsigned hin[RSZP4];
    __shared__ unsigned hsrc[RSZP4];
    int c = blockIdx.x % NC_MS;          // bid%8 == c%8 -> chunk replicas share an XCD L2
    int r = blockIdx.x / NC_MS;
    int base = r * RSZ;
    int t = threadIdx.x;
    for (int w = t; w < RSZP4; w += MSB) { hin[w] = 0u; hsrc[w] = 0u; }
    __syncthreads();
    int e0 = c * chunk, e1 = min(e, e0 + chunk);
    for (int i = e0 + t; i < e1; i += MSB) {
        int s = src[i], d = dst[i];
        unsigned ud = (unsigned)(d - base);
        unsigned us = (unsigned)(s - base);
        if (ud < (unsigned)RSZ) atomicAdd(&hin[ud >> 2], 1u << ((ud & 3) * 8));
        if (us < (unsigned)RSZ) atomicAdd(&hsrc[us >> 2], 1u << ((us & 3) * 8));
    }
    __syncthreads();
    int lim = min(RSZ, n - base);
    if (lim <= 0) return;
    int plim = (lim + 3) >> 2;
    unsigned* gin  = rep_in  + (size_t)c * nwords + (base >> 2);
    unsigned* gsrc = rep_src + (size_t)c * nwords + (base >> 2);
    for (int w = t; w < plim; w += MSB) { gin[w] = hin[w]; gsrc[w] = hsrc[w]; }
}

// reduce u8 replicas: dinv + out-counts; convert src replicas in place to per-chunk
// u8 exclusive prefixes (prefix <= node degree ~30 << 255).
__global__ __launch_bounds__(256) void k_msreduce(const unsigned* __restrict__ rep_in,
                                                  unsigned* __restrict__ rep_src,   // -> pref
                                                  float* __restrict__ dinv,
                                                  unsigned* __restrict__ counts_src,
                                                  int n, int nwords) {
    int i4 = blockIdx.x * 256 + threadIdx.x;
    if (i4 >= nwords) return;
    unsigned s0 = 0, s1 = 0, s2 = 0, s3 = 0;
    unsigned r0 = 0, r1 = 0, r2 = 0, r3 = 0;
#pragma unroll 4
    for (int c = 0; c < NC_MS; ++c) {
        unsigned vi = rep_in[(size_t)c * nwords + i4];
        s0 += vi & 0xFFu; s1 += (vi >> 8) & 0xFFu; s2 += (vi >> 16) & 0xFFu; s3 += vi >> 24;
        unsigned vs = rep_src[(size_t)c * nwords + i4];
        rep_src[(size_t)c * nwords + i4] = r0 | (r1 << 8) | (r2 << 16) | (r3 << 24);
        r0 += vs & 0xFFu; r1 += (vs >> 8) & 0xFFu; r2 += (vs >> 16) & 0xFFu; r3 += vs >> 24;
    }
    int i = i4 * 4;
    unsigned sv[4] = {s0, s1, s2, s3};
    unsigned rv[4] = {r0, r1, r2, r3};
#pragma unroll
    for (int q = 0; q < 4; ++q) {
        if (i + q < n) {
            dinv[i + q] = rsqrtf((float)(sv[q] + 1u));
            counts_src[i + q] = rv[q];
        }
    }
}

// ---------------- 2-level exclusive scan (edge counts) ----------------
__global__ __launch_bounds__(256) void k_blocksum(const unsigned* __restrict__ counts,
                                                  unsigned* __restrict__ partials, int n) {
    __shared__ unsigned s[256];
    int base = blockIdx.x * 1024;
    unsigned sum = 0;
    for (int j = threadIdx.x; j < 1024; j += 256) {
        int i = base + j;
        sum += (i < n) ? counts[i] : 0u;
    }
    s[threadIdx.x] = sum;
    __syncthreads();
    for (int off = 128; off > 0; off >>= 1) {
        if (threadIdx.x < (unsigned)off) s[threadIdx.x] += s[threadIdx.x + off];
        __syncthreads();
    }
    if (threadIdx.x == 0) partials[blockIdx.x] = s[0];
}

__global__ __launch_bounds__(128) void k_scanpartials(unsigned* __restrict__ partials, int nb) {
    __shared__ unsigned s[128];
    int t = threadIdx.x;
    s[t] = (t < nb) ? partials[t] : 0u;
    __syncthreads();
    if (t == 0) {
        unsigned run = 0;
        for (int i = 0; i < nb; ++i) { unsigned v = s[i]; s[i] = run; run += v; }
    }
    __syncthreads();
    if (t < nb) partials[t] = s[t];
}

__global__ __launch_bounds__(256) void k_scanblock(const unsigned* __restrict__ counts,
                                                   const unsigned* __restrict__ partials,
                                                   unsigned* __restrict__ row_start, int n) {
    __shared__ unsigned s[256];
    int base = blockIdx.x * 1024;
    int t = threadIdx.x;
    unsigned v[4];
    unsigned tsum = 0;
#pragma unroll
    for (int j = 0; j < 4; ++j) {
        int i = base + t * 4 + j;
        v[j] = (i < n) ? counts[i] : 0u;
        tsum += v[j];
    }
    s[t] = tsum;
    __syncthreads();
    for (int off = 1; off < 256; off <<= 1) {
        unsigned x = (t >= off) ? s[t - off] : 0u;
        __syncthreads();
        s[t] += x;
        __syncthreads();
    }
    unsigned excl = (t > 0 ? s[t - 1] : 0u) + partials[blockIdx.x];
#pragma unroll
    for (int j = 0; j < 4; ++j) {
        int i = base + t * 4 + j;
        if (i < n) {
            row_start[i] = excl;
            excl += v[j];
            if (i == n - 1) row_start[n] = excl;
        }
    }
}

// ---------------- edge multi-split fill (u8 LDS cursors) ----------------
__global__ __launch_bounds__(MSB) void k_msfill(const int* __restrict__ src, const int* __restrict__ dst,
                                                const int* __restrict__ batch,
                                                const unsigned* __restrict__ row_start,
                                                const unsigned* __restrict__ pref,   // u8-packed [NC][nwords]
                                                const float* __restrict__ dinv,
                                                uint2* __restrict__ euv,
                                                int e, int n, int chunk, int nwords) {
    __shared__ unsigned cur[RSZP4];
    int c = blockIdx.x % NC_MS;
    int r = blockIdx.x / NC_MS;
    int base = r * RSZ;
    int t = threadIdx.x;
    for (int w = t; w < RSZP4; w += MSB) cur[w] = 0u;
    __syncthreads();
    int e0 = c * chunk, e1 = min(e, e0 + chunk);
    const unsigned* prefc = pref + (size_t)c * nwords;
    for (int i = e0 + t; i < e1; i += MSB) {
        int s = src[i];
        unsigned us = (unsigned)(s - base);
        if (us < (unsigned)RSZ) {
            int d = dst[i];
            unsigned sh = (us & 3) * 8;
            unsigned old = atomicAdd(&cur[us >> 2], 1u << sh);
            unsigned slot = (old >> sh) & 0xFFu;
            unsigned p8 = (prefc[(unsigned)s >> 2] >> ((s & 3) * 8)) & 0xFFu;
            unsigned pos = row_start[s] + p8 + slot;
            uint2 pv;
            pv.x = (unsigned)d | ((unsigned)batch[d] << 17);
            pv.y = f_as_u(dinv[s] * dinv[d]);
            euv[pos] = pv;
        }
    }
}

// ---------------- word counting sort ----------------
__global__ __launch_bounds__(256) void k_wcount(const int* __restrict__ x,
                                                unsigned* __restrict__ wcnt, int n) {
    int j = blockIdx.x * 256 + threadIdx.x;
    if (j >= n) return;
    atomicAdd(&wcnt[x[2 * j + 1]], 1u);
}

// single-block scan over VOC counts -> wstart (replaces 3-kernel pipeline)
__global__ __launch_bounds__(1024) void k_wscan(const unsigned* __restrict__ wcnt,
                                                unsigned* __restrict__ wstart) {
    __shared__ unsigned s[1024];
    int t = threadIdx.x;
    int lo = t * 10;                 // 1000 threads x 10 = VOC
    unsigned v[10];
    unsigned sum = 0;
    if (lo < VOC) {
#pragma unroll
        for (int q = 0; q < 10; ++q) { v[q] = wcnt[lo + q]; sum += v[q]; }
    }
    s[t] = sum;
    __syncthreads();
    for (int off = 1; off < 1024; off <<= 1) {
        unsigned x = (t >= off) ? s[t - off] : 0u;
        __syncthreads();
        s[t] += x;
        __syncthreads();
    }
    if (lo < VOC) {
        unsigned excl = (t > 0) ? s[t - 1] : 0u;
#pragma unroll
        for (int q = 0; q < 10; ++q) { wstart[lo + q] = excl; excl += v[q]; }
    }
    if (t == 1023) wstart[VOC] = s[1023];
}

__global__ __launch_bounds__(256) void k_wfill(const int* __restrict__ x,
                                               const unsigned* __restrict__ wstart,
                                               unsigned* __restrict__ wcur,
                                               unsigned* __restrict__ sorted, int n) {
    int j = blockIdx.x * 256 + threadIdx.x;
    if (j >= n) return;
    int w = x[2 * j + 1];
    unsigned pos = wstart[w] + atomicAdd(&wcur[w], 1u);
    sorted[pos] = (unsigned)j;
}

// ---------------- per-word column sums: tw[w][g] (plain stores) ----------------
__global__ __launch_bounds__(256) void k_twfill(const __half* __restrict__ Y3,
                                                const unsigned* __restrict__ sorted,
                                                const unsigned* __restrict__ wstart,
                                                float* __restrict__ tw) {
    int w = blockIdx.x * 4 + (threadIdx.x >> 6);
    int g = threadIdx.x & 63;
    if (w >= VOC) return;
    unsigned i0 = wstart[w], i1 = wstart[w + 1];
    float s = 0.f;
    unsigned i = i0;
    for (; i + 2 <= i1; i += 2) {
        unsigned j0 = sorted[i], j1 = sorted[i + 1];
        s += __half2float(Y3[(size_t)j0 * NG + g]) + __half2float(Y3[(size_t)j1 * NG + g]);
    }
    if (i < i1) {
        unsigned j0 = sorted[i];
        s += __half2float(Y3[(size_t)j0 * NG + g]);
    }
    tw[(size_t)w * NG + g] = s;
}

// ---------------- atom counting sort: LDS-hist multi-split (no device atomics) ----------------
__global__ __launch_bounds__(256) void k_amscount(const int* __restrict__ x,
                                                  unsigned* __restrict__ rep_a,
                                                  int n, int chunk) {
    __shared__ unsigned h[NATOM];
    int c = blockIdx.x;
    int t = threadIdx.x;
    if (t < NATOM) h[t] = 0u;
    __syncthreads();
    int j0 = c * chunk, j1 = min(n, j0 + chunk);
    for (int j = j0 + t; j < j1; j += 256) atomicAdd(&h[x[2 * j]], 1u);
    __syncthreads();
    if (t < NATOM) rep_a[c * NATOM + t] = h[t];
}

__global__ __launch_bounds__(64) void k_amsscan(unsigned* __restrict__ rep_a,
                                                unsigned* __restrict__ astart, int n) {
    __shared__ unsigned tot[NATOM];
    int t = threadIdx.x;
    if (t < NATOM) {
        unsigned run = 0;
        for (int c = 0; c < NC_A; ++c) {
            unsigned v = rep_a[c * NATOM + t];
            rep_a[c * NATOM + t] = run;
            run += v;
        }
        tot[t] = run;
    }
    __syncthreads();
    if (t == 0) {
        unsigned run = 0;
        for (int a = 0; a < NATOM; ++a) { astart[a] = run; run += tot[a]; }
        astart[NATOM] = run;   // == n
    }
}

__global__ __launch_bounds__(256) void k_amsfill(const int* __restrict__ x,
                                                 const unsigned* __restrict__ astart,
                                                 const unsigned* __restrict__ rep_a,
                                                 unsigned* __restrict__ asorted,
                                                 int n, int chunk) {
    __shared__ unsigned cur[NATOM];
    __shared__ unsigned base[NATOM];
    int c = blockIdx.x;
    int t = threadIdx.x;
    if (t < NATOM) {
        cur[t] = 0u;
        base[t] = astart[t] + rep_a[c * NATOM + t];
    }
    __syncthreads();
    int j0 = c * chunk, j1 = min(n, j0 + chunk);
    for (int j = j0 + t; j < j1; j += 256) {
        int a = x[2 * j];
        unsigned slot = atomicAdd(&cur[a], 1u);
        asorted[base[a] + slot] = (unsigned)j;
    }
}

// ---------------- atom gather: register sums, plain-store partials ----------------
__global__ __launch_bounds__(256) void k_tafill(const __half* __restrict__ Y3,
                                                const unsigned* __restrict__ asorted,
                                                const unsigned* __restrict__ astart,
                                                float* __restrict__ tap) {
    int wid = blockIdx.x * 4 + (threadIdx.x >> 6);
    if (wid >= NATOM * ASL) return;
    int a  = wid >> 7;            // / ASL
    int sl = wid & (ASL - 1);
    int g  = threadIdx.x & 63;
    unsigned i0 = astart[a], i1 = astart[a + 1];
    unsigned len = i1 - i0;
    unsigned lo = i0 + (unsigned)((unsigned long long)len * sl / ASL);
    unsigned hi = i0 + (unsigned)((unsigned long long)len * (sl + 1) / ASL);
    float s = 0.f;
    unsigned i = lo;
    for (; i + 2 <= hi; i += 2) {
        unsigned j0 = asorted[i], j1 = asorted[i + 1];
        s += __half2float(Y3[(size_t)j0 * NG + g]) + __half2float(Y3[(size_t)j1 * NG + g]);
    }
    if (i < hi) s += __half2float(Y3[(size_t)asorted[i] * NG + g]);
    tap[((size_t)a * ASL + sl) * NG + g] = s;
}

__global__ __launch_bounds__(256) void k_tareduce(const float* __restrict__ tap,
                                                  float* __restrict__ ta) {
    int i = blockIdx.x * 256 + threadIdx.x;
    if (i >= NATOM * NG) return;
    int a = i >> 6;
    int g = i & 63;
    float s = 0.f;
    for (int sl = 0; sl < ASL; ++sl) s += tap[((size_t)a * ASL + sl) * NG + g];
    ta[i] = s;
}

// ---------------- graph boundaries (batch sorted) ----------------
__global__ __launch_bounds__(128) void k_gstart(const int* __restrict__ batch,
                                                int* __restrict__ gstart, int n, int ngraph) {
    int g = threadIdx.x;
    if (g > ngraph) return;
    if (g == ngraph) { gstart[g] = n; return; }
    int lo = 0, hi = n;
    while (lo < hi) {
        int mid = (lo + hi) >> 1;
        if (batch[mid] < g) lo = mid + 1; else hi = mid;
    }
    gstart[g] = lo;
}

// ---------------- hop 1 (fp16 out, 4-wide unrolled edge loop) ----------------
__global__ __launch_bounds__(256) void k_y1(const int* __restrict__ batch,
                                            const float* __restrict__ dinv,
                                            const unsigned* __restrict__ row_start,
                                            const uint2* __restrict__ euv,
                                            __half* __restrict__ Y1, int n) {
    int idx = blockIdx.x * 256 + threadIdx.x;
    if (idx >= n * 16) return;
    int j = idx >> 4;
    int c4 = idx & 15;
    int cb = c4 * 4;
    float a0 = 0.f, a1 = 0.f, a2 = 0.f, a3 = 0.f;
    {
        int bj = batch[j];
        float dj = dinv[j];
        float sn = dj * dj;
        a0 += (bj == cb + 0) ? sn : 0.f;
        a1 += (bj == cb + 1) ? sn : 0.f;
        a2 += (bj == cb + 2) ? sn : 0.f;
        a3 += (bj == cb + 3) ? sn : 0.f;
    }
    unsigned e0 = row_start[j], e1 = row_start[j + 1];
    unsigned e = e0;
    for (; e + 4 <= e1; e += 4) {
        uint2 p0 = euv[e], p1 = euv[e + 1], p2 = euv[e + 2], p3 = euv[e + 3];
        int b0 = (int)(p0.x >> 17), b1 = (int)(p1.x >> 17);
        int b2 = (int)(p2.x >> 17), b3 = (int)(p3.x >> 17);
        float v0 = u_as_f(p0.y), v1 = u_as_f(p1.y);
        float v2 = u_as_f(p2.y), v3 = u_as_f(p3.y);
        a0 += ((b0 == cb + 0) ? v0 : 0.f) + ((b1 == cb + 0) ? v1 : 0.f)
            + ((b2 == cb + 0) ? v2 : 0.f) + ((b3 == cb + 0) ? v3 : 0.f);
        a1 += ((b0 == cb + 1) ? v0 : 0.f) + ((b1 == cb + 1) ? v1 : 0.f)
            + ((b2 == cb + 1) ? v2 : 0.f) + ((b3 == cb + 1) ? v3 : 0.f);
        a2 += ((b0 == cb + 2) ? v0 : 0.f) + ((b1 == cb + 2) ? v1 : 0.f)
            + ((b2 == cb + 2) ? v2 : 0.f) + ((b3 == cb + 2) ? v3 : 0.f);
        a3 += ((b0 == cb + 3) ? v0 : 0.f) + ((b1 == cb + 3) ? v1 : 0.f)
            + ((b2 == cb + 3) ? v2 : 0.f) + ((b3 == cb + 3) ? v3 : 0.f);
    }
    for (; e < e1; ++e) {
        uint2 p = euv[e];
        int bd = (int)(p.x >> 17);
        float v = u_as_f(p.y);
        a0 += (bd == cb + 0) ? v : 0.f;
        a1 += (bd == cb + 1) ? v : 0.f;
        a2 += (bd == cb + 2) ? v : 0.f;
        a3 += (bd == cb + 3) ? v : 0.f;
    }
    H4 o;
    o.h[0] = __float2half(a0); o.h[1] = __float2half(a1);
    o.h[2] = __float2half(a2); o.h[3] = __float2half(a3);
    *(uint2*)&Y1[(size_t)j * NG + cb] = o.u2;
}

// ---------------- Y-hop fp16 -> fp16 (4-wide unrolled gather for MLP) ----------------
__global__ __launch_bounds__(256) void k_yprop(const __half* __restrict__ Yin,
                                               const float* __restrict__ dinv,
                                               const unsigned* __restrict__ row_start,
                                               const uint2* __restrict__ euv,
                                               __half* __restrict__ Yout, int n) {
    int idx = blockIdx.x * 256 + threadIdx.x;
    if (idx >= n * 16) return;
    int j = idx >> 4;
    int c4 = idx & 15;
    int cb = c4 * 4;
    float dj = dinv[j];
    float sn = dj * dj;
    H4 s; s.u2 = *(const uint2*)&Yin[(size_t)j * NG + cb];
    float a0 = sn * __half2float(s.h[0]);
    float a1 = sn * __half2float(s.h[1]);
    float a2 = sn * __half2float(s.h[2]);
    float a3 = sn * __half2float(s.h[3]);
    unsigned e0 = row_start[j], e1 = row_start[j + 1];
    unsigned e = e0;
    for (; e + 4 <= e1; e += 4) {
        uint2 p0 = euv[e], p1 = euv[e + 1], p2 = euv[e + 2], p3 = euv[e + 3];
        float v0 = u_as_f(p0.y), v1 = u_as_f(p1.y);
        float v2 = u_as_f(p2.y), v3 = u_as_f(p3.y);
        H4 m0; m0.u2 = *(const uint2*)&Yin[(size_t)(p0.x & 0x1FFFFu) * NG + cb];
        H4 m1; m1.u2 = *(const uint2*)&Yin[(size_t)(p1.x & 0x1FFFFu) * NG + cb];
        H4 m2; m2.u2 = *(const uint2*)&Yin[(size_t)(p2.x & 0x1FFFFu) * NG + cb];
        H4 m3; m3.u2 = *(const uint2*)&Yin[(size_t)(p3.x & 0x1FFFFu) * NG + cb];
        a0 += v0 * __half2float(m0.h[0]) + v1 * __half2float(m1.h[0])
            + v2 * __half2float(m2.h[0]) + v3 * __half2float(m3.h[0]);
        a1 += v0 * __half2float(m0.h[1]) + v1 * __half2float(m1.h[1])
            + v2 * __half2float(m2.h[1]) + v3 * __half2float(m3.h[1]);
        a2 += v0 * __half2float(m0.h[2]) + v1 * __half2float(m1.h[2])
            + v2 * __half2float(m2.h[2]) + v3 * __half2float(m3.h[2]);
        a3 += v0 * __half2float(m0.h[3]) + v1 * __half2float(m1.h[3])
            + v2 * __half2float(m2.h[3]) + v3 * __half2float(m3.h[3]);
    }
    for (; e < e1; ++e) {
        uint2 p0 = euv[e];
        float v0 = u_as_f(p0.y);
        H4 m0; m0.u2 = *(const uint2*)&Yin[(size_t)(p0.x & 0x1FFFFu) * NG + cb];
        a0 += v0 * __half2float(m0.h[0]);
        a1 += v0 * __half2float(m0.h[1]);
        a2 += v0 * __half2float(m0.h[2]);
        a3 += v0 * __half2float(m0.h[3]);
    }
    H4 o;
    o.h[0] = __float2half(a0); o.h[1] = __float2half(a1);
    o.h[2] = __float2half(a2); o.h[3] = __float2half(a3);
    *(uint2*)&Yout[(size_t)j * NG + cb] = o.u2;
}

// ---------------- column sums (fp16 input), XCC-replicated output ----------------
__global__ __launch_bounds__(256) void k_colsumh(const __half* __restrict__ Y,
                                                 float* __restrict__ su8, int n) {
    __shared__ float red[16][NG];
    int t = threadIdx.x;
    int cg = t & 15;
    int sr = t >> 4;
    float a0 = 0.f, a1 = 0.f, a2 = 0.f, a3 = 0.f;
    int stride = gridDim.x * 16;
    for (int j = blockIdx.x * 16 + sr; j < n; j += stride) {
        H4 v; v.u2 = *(const uint2*)&Y[(size_t)j * NG + cg * 4];
        a0 += __half2float(v.h[0]);
        a1 += __half2float(v.h[1]);
        a2 += __half2float(v.h[2]);
        a3 += __half2float(v.h[3]);
    }
    red[sr][cg * 4 + 0] = a0;
    red[sr][cg * 4 + 1] = a1;
    red[sr][cg * 4 + 2] = a2;
    red[sr][cg * 4 + 3] = a3;
    __syncthreads();
    if (t < NG) {
        float s = 0.f;
#pragma unroll
        for (int q = 0; q < 16; ++q) s += red[q][t];
        int r = xcc_id();
        __hip_atomic_fetch_add(&su8[r * NG + t], s,
                               __ATOMIC_RELAXED, __HIP_MEMORY_SCOPE_WORKGROUP);
    }
}

// ---------------- tiled word contraction: Gpart[kc] = tw_chunk^T @ wt_chunk ----------------
__global__ __launch_bounds__(256) void k_wgemm2(const float* __restrict__ T,    // [KPAD][64]
                                                const float* __restrict__ Tab,  // [10000][300]
                                                float* __restrict__ Gpart) {
    __shared__ float Asm[32 * 64];
    __shared__ float Bsm[32 * 64];
    const int t = threadIdx.x;
    const int tg = t >> 4;
    const int tc = t & 15;
    const int c0 = blockIdx.x * 64;
    const int kb = blockIdx.y * WGK;

    float acc[4][4] = {};

    for (int sub = 0; sub < WGK / 32; ++sub) {
        int kbase = kb + sub * 32;
#pragma unroll
        for (int r2 = 0; r2 < 2; ++r2) {
            int idx4 = r2 * 256 + t;
            int k = idx4 >> 4, g4 = idx4 & 15;
            float4 v = *(const float4*)&T[(size_t)(kbase + k) * 64 + g4 * 4];
            *(float4*)&Asm[k * 64 + g4 * 4] = v;
        }
#pragma unroll
        for (int r2 = 0; r2 < 2; ++r2) {
            int idx4 = r2 * 256 + t;
            int k = idx4 >> 4, c4i = idx4 & 15;
            int gk = kbase + k;
            int cb2 = c0 + c4i * 4;
            float4 v;
            if (gk < VOC && cb2 + 3 < 300) {
                v = *(const float4*)&Tab[(size_t)gk * 300 + cb2];
            } else {
                float tmp[4];
#pragma unroll
                for (int q = 0; q < 4; ++q)
                    tmp[q] = (gk < VOC && cb2 + q < 300) ? Tab[(size_t)gk * 300 + cb2 + q] : 0.f;
                v.x = tmp[0]; v.y = tmp[1]; v.z = tmp[2]; v.w = tmp[3];
            }
            *(float4*)&Bsm[k * 64 + c4i * 4] = v;
        }
        __syncthreads();
#pragma unroll 8
        for (int k = 0; k < 32; ++k) {
            float4 a4 = *(const float4*)&Asm[k * 64 + tg * 4];
            float4 b4 = *(const float4*)&Bsm[k * 64 + tc * 4];
            float a[4] = {a4.x, a4.y, a4.z, a4.w};
            float b[4] = {b4.x, b4.y, b4.z, b4.w};
#pragma unroll
            for (int i = 0; i < 4; ++i)
#pragma unroll
                for (int jj = 0; jj < 4; ++jj) acc[i][jj] += a[i] * b[jj];
        }
        __syncthreads();
    }

    float* gp = Gpart + (size_t)blockIdx.y * (NG * 300);
#pragma unroll
    for (int i = 0; i < 4; ++i) {
        int g = tg * 4 + i;
#pragma unroll
        for (int jj = 0; jj < 4; ++jj) {
            int c = c0 + tc * 4 + jj;
            if (c < 300) gp[g * 300 + c] = acc[i][jj];
        }
    }
}

// reduce k-chunk partials into G0 (few atomics; G0 zeroed)
__global__ __launch_bounds__(256) void k_greduce(const float* __restrict__ Gpart,
                                                 float* __restrict__ G0) {
    int k = blockIdx.x * 256 + threadIdx.x;
    if (k >= NG * 300) return;
    int p0 = blockIdx.y * (NKC / 8);
    int p1 = p0 + (NKC / 8);
    float s = 0.f;
    for (int p = p0; p < p1; ++p) s += Gpart[(size_t)p * (NG * 300) + k];
    atomicAdd(&G0[k], s);
}

// ---------------- atom contraction: K=41 ----------------
__global__ __launch_bounds__(256) void k_agemm(const float* __restrict__ T,
                                               const float* __restrict__ Tab,
                                               float* __restrict__ G0) {
    int j = blockIdx.x * 256 + threadIdx.x;
    if (j >= NG * 300) return;
    int g = j / 300, c = j - g * 300;
    float acc = 0.f;
#pragma unroll
    for (int k = 0; k < 41; ++k) acc += T[(size_t)k * NG + g] * Tab[(size_t)k * 300 + c];
    atomicAdd(&G0[j], acc);
}

// ---------------- small GEMM split-k ----------------
__global__ __launch_bounds__(256) void k_smm(const float* __restrict__ A,
                                             const float* __restrict__ W,
                                             float* __restrict__ C) {
    int j = blockIdx.x * 256 + threadIdx.x;
    if (j >= NG * 300) return;
    int g = j / 300, c = j - g * 300;
    int k0 = blockIdx.y * 60;
    float acc = 0.f;
#pragma unroll 1
    for (int k = k0; k < k0 + 60; k += 4) {
        float a0 = A[g * 300 + k + 0], a1 = A[g * 300 + k + 1];
        float a2 = A[g * 300 + k + 2], a3 = A[g * 300 + k + 3];
        float w0 = W[(k + 0) * 300 + c], w1 = W[(k + 1) * 300 + c];
        float w2 = W[(k + 2) * 300 + c], w3 = W[(k + 3) * 300 + c];
        acc += a0 * w0 + a1 * w1 + a2 * w2 + a3 * w3;
    }
    atomicAdd(&C[j], acc);
}

// ---------------- vector-matrix ----------------
__global__ __launch_bounds__(256) void k_vec(const float* __restrict__ vin,
                                             const float* __restrict__ W,
                                             float* __restrict__ r_out) {
    int c = blockIdx.x * 256 + threadIdx.x;
    if (c >= 300) return;
    int k0 = blockIdx.y * 75;
    float acc = 0.f;
    for (int k = k0; k < k0 + 75; ++k) acc += vin[k] * W[k * 300 + c];
    atomicAdd(&r_out[c], acc);
}

// ---------------- final assembly ----------------
__global__ __launch_bounds__(256) void k_out(const float* __restrict__ T3,
                                             const float* __restrict__ su1,
                                             const float* __restrict__ su2,
                                             const int* __restrict__ gstart,
                                             const float* __restrict__ r1,
                                             const float* __restrict__ r2,
                                             const float* __restrict__ b,
                                             float* __restrict__ out) {
    int j = blockIdx.x * 256 + threadIdx.x;
    if (j >= NG * 300) return;
    int g = j / 300, c = j - g * 300;
    int cnt = gstart[g + 1] - gstart[g];
    float s1 = 0.f, s2 = 0.f;
#pragma unroll
    for (int r = 0; r < 8; ++r) {
        s1 += su1[r * NG + g];
        s2 += su2[r * NG + g];
    }
    float v = T3[j] + s2 * r2[c] + s1 * r1[c] + (float)cnt * b[c];
    out[j] = v / (float)(cnt > 0 ? cnt : 1);
}

// ---------------- launch ----------------
extern "C" void kernel_launch(void* const* d_in, const int* in_sizes, int n_in,
                              void* d_out, int out_size, void* d_ws, size_t ws_size,
                              hipStream_t stream) {
    const int*   x     = (const int*)d_in[0];
    const int*   ei    = (const int*)d_in[1];
    const int*   batch = (const int*)d_in[2];
    const float* at    = (const float*)d_in[3];
    const float* wt    = (const float*)d_in[4];
    const float* W     = (const float*)d_in[5];
    const float* b     = (const float*)d_in[6];

    const int n = in_sizes[0] / 2;   // 100000
    const int e = in_sizes[1] / 2;   // 800000

    char* ws = (char*)d_ws;
    size_t off = 0;
    auto carve = [&](size_t bytes) {
        void* p = ws + off;
        off += (bytes + 255) & ~(size_t)255;
        return p;
    };
    __half*   Y1        = (__half*)carve((size_t)n * NG * 2);
    __half*   Y2        = (__half*)carve((size_t)n * NG * 2);
    __half*   Y3        = (__half*)carve((size_t)n * NG * 2);
    uint2*    euv       = (uint2*)carve((size_t)e * 8);
    float*    dinv      = (float*)carve((size_t)n * 4);
    unsigned* counts_src= (unsigned*)carve((size_t)n * 4);
    unsigned* row_start = (unsigned*)carve((size_t)(n + 1) * 4);
    unsigned* partials  = (unsigned*)carve(1024 * 4);
    int*      gstart    = (int*)carve(65 * 4);
    unsigned* wstart    = (unsigned*)carve((size_t)(VOC + 1) * 4);
    unsigned* sorted    = (unsigned*)carve((size_t)n * 4);
    unsigned* asorted   = (unsigned*)carve((size_t)n * 4);
    unsigned* astart    = (unsigned*)carve((NATOM + 1) * 4);
    unsigned* rep_a     = (unsigned*)carve((size_t)NC_A * NATOM * 4);
    float*    tap       = (float*)carve((size_t)NATOM * ASL * NG * 4);  // 1.34 MB
    // ---- zero region B ----
    char*     zB0       = (char*)carve(0);
    float*    su1       = (float*)carve((size_t)8 * NG * 4);
    float*    su2       = (float*)carve((size_t)8 * NG * 4);
    float*    ta        = (float*)carve((size_t)NATOM * NG * 4);
    float*    tw        = (float*)carve((size_t)KPAD * NG * 4);   // pad rows must be zero
    float*    G0        = (float*)carve((size_t)NG * 300 * 4);
    float*    r1        = (float*)carve(300 * 4);
    float*    r2        = (float*)carve(300 * 4);
    float*    T1        = (float*)carve((size_t)NG * 300 * 4);
    float*    T2        = (float*)carve((size_t)NG * 300 * 4);
    float*    T3        = (float*)carve((size_t)NG * 300 * 4);
    unsigned* wcnt      = (unsigned*)carve((size_t)VOC * 4);
    unsigned* wcur      = (unsigned*)carve((size_t)VOC * 4);
    char*     zB1       = (char*)carve(0);

    const int* src = ei;
    const int* dst = ei + e;

    // aliases (lifetime-disjoint):
    //  u8 edge replicas (NC_MS * n = 12.8 MB each) in Y1/Y2 (dead before k_y1 / yprop#1 write them)
    //  Gpart (160*19200*4 = 12.3 MB) in Y1 (dead after yprop#2 reads Y2; Y1 dead earlier)
    unsigned* rep_in  = (unsigned*)Y1;
    unsigned* rep_src = (unsigned*)Y2;
    float*    Gpart   = (float*)Y1;

    hipMemsetAsync(zB0, 0, (size_t)(zB1 - zB0), stream);

    const int nwords = (n + 3) / 4;                // u8-packed words per chunk
    const int chunk  = (e + NC_MS - 1) / NC_MS;    // 6250
    const int achunk = (n + NC_A - 1) / NC_A;      // 782

    // edge reverse-CSR (u8 multi-split: 4 ranges -> half the redundant edge reads)
    k_mscount<<<NRNG * NC_MS, MSB, 0, stream>>>(src, dst, rep_in, rep_src, e, n, chunk, nwords);
    k_msreduce<<<(nwords + 255) / 256, 256, 0, stream>>>(rep_in, rep_src, dinv, counts_src, n, nwords);
    int NB = (n + 1023) / 1024;      // 98
    k_blocksum<<<NB, 256, 0, stream>>>(counts_src, partials, n);
    k_scanpartials<<<1, 128, 0, stream>>>(partials, NB);
    k_scanblock<<<NB, 256, 0, stream>>>(counts_src, partials, row_start, n);
    k_msfill<<<NRNG * NC_MS, MSB, 0, stream>>>(src, dst, batch, row_start, rep_src, dinv, euv, e, n, chunk, nwords);
    k_gstart<<<1, 128, 0, stream>>>(batch, gstart, n, NGRAPH_C);

    // word counting sort (atomic cursor; single-block scan)
    int nb256 = (n + 255) / 256;
    k_wcount<<<nb256, 256, 0, stream>>>(x, wcnt, n);
    k_wscan<<<1, 1024, 0, stream>>>(wcnt, wstart);
    k_wfill<<<nb256, 256, 0, stream>>>(x, wstart, wcur, sorted, n);

    // atom counting sort (LDS-hist multi-split, no device atomics)
    k_amscount<<<NC_A, 256, 0, stream>>>(x, rep_a, n, achunk);
    k_amsscan<<<1, 64, 0, stream>>>(rep_a, astart, n);
    k_amsfill<<<NC_A, 256, 0, stream>>>(x, astart, rep_a, asorted, n, achunk);

    // indicator propagation: Y1 -> Y2 -> Y3 (fp16)
    int yb = (n * 16 + 255) / 256;   // 6250
    k_y1<<<yb, 256, 0, stream>>>(batch, dinv, row_start, euv, Y1, n);
    k_colsumh<<<512, 256, 0, stream>>>(Y1, su1, n);
    k_yprop<<<yb, 256, 0, stream>>>(Y1, dinv, row_start, euv, Y2, n);
    k_colsumh<<<512, 256, 0, stream>>>(Y2, su2, n);
    k_yprop<<<yb, 256, 0, stream>>>(Y2, dinv, row_start, euv, Y3, n);

    // contractions -> G0 = Y3^T H0
    k_tafill<<<(NATOM * ASL + 3) / 4, 256, 0, stream>>>(Y3, asorted, astart, tap);
    k_tareduce<<<(NATOM * NG + 255) / 256, 256, 0, stream>>>(tap, ta);
    k_twfill<<<(VOC + 3) / 4, 256, 0, stream>>>(Y3, sorted, wstart, tw);
    {
        dim3 gw(5, NKC);   // 5 c-tiles x 160 k-chunks of 64 (800 blocks)
        k_wgemm2<<<gw, 256, 0, stream>>>(tw, wt, Gpart);
        dim3 gr((NG * 300 + 255) / 256, 8);
        k_greduce<<<gr, 256, 0, stream>>>(Gpart, G0);
    }
    k_agemm<<<(NG * 300 + 255) / 256, 256, 0, stream>>>(ta, at, G0);

    // W chain: T3 = G0 * W^3
    {
        dim3 gs((NG * 300 + 255) / 256, 5);
        k_smm<<<gs, 256, 0, stream>>>(G0, W, T1);
        k_smm<<<gs, 256, 0, stream>>>(T1, W, T2);
        k_smm<<<gs, 256, 0, stream>>>(T2, W, T3);
        dim3 gv(2, 4);
        k_vec<<<gv, 256, 0, stream>>>(b, W, r1);
        k_vec<<<gv, 256, 0, stream>>>(r1, W, r2);
    }

    k_out<<<(NG * 300 + 255) / 256, 256, 0, stream>>>(T3, su1, su2, gstart, r1, r2, b, (float*)d_out);
}

// Round 11
// 297.667 us; speedup vs baseline: 1.2394x; 1.0921x over previous
//
#include <hip/hip_runtime.h>
#include <hip/hip_fp16.h>

#define NG 64              // graphs (= Y feature width)
#define NGRAPH_C 64

// edge multi-split geometry (u8-packed LDS histograms)
#define RSZ 25000          // nodes per range (4 ranges for n=100000)
#define RSZP4 6250         // packed u8 quads per range
#define NC_MS 128          // edge chunks
#define NRNG 4
#define MSB 1024           // threads/block (2 blk/CU x 16 waves)

// word contraction geometry
#define VOC 10000
#define KPAD 10240         // padded K for wgemm (80 chunks of 128)
#define NKC 80             // split-k chunks
#define WGK 128            // K per chunk

// atom sort geometry
#define NATOM 41
#define NC_A 128           // node chunks for x sort kernels
#define ASL 128            // gather slices per atom
#define TW_BLKS ((VOC + 3) / 4)            // 2500
#define TA_BLKS ((NATOM * ASL + 3) / 4)    // 1312

// ---- bit casts ----
__device__ __forceinline__ unsigned f_as_u(float f) { union { float f; unsigned u; } c; c.f = f; return c.u; }
__device__ __forceinline__ float u_as_f(unsigned u) { union { unsigned u; float f; } c; c.u = u; return c.f; }

// XCD id (0..7)
__device__ __forceinline__ int xcc_id() {
    unsigned x;
    asm volatile("s_getreg_b32 %0, hwreg(HW_REG_XCC_ID)" : "=s"(x));
    return (int)(x & 7u);
}

union H4 { uint2 u2; __half h[4]; };

// ---------------- edge multi-split count (u8 LDS hist) ----------------
__global__ __launch_bounds__(MSB) void k_mscount(const int* __restrict__ src, const int* __restrict__ dst,
                                                 unsigned* __restrict__ rep_in,
                                                 unsigned* __restrict__ rep_src,
                                                 int e, int n, int chunk, int nwords) {
    __shared__ unsigned hin[RSZP4];
    __shared__ unsigned hsrc[RSZP4];
    int c = blockIdx.x % NC_MS;
    int r = blockIdx.x / NC_MS;
    int base = r * RSZ;
    int t = threadIdx.x;
    for (int w = t; w < RSZP4; w += MSB) { hin[w] = 0u; hsrc[w] = 0u; }
    __syncthreads();
    int e0 = c * chunk, e1 = min(e, e0 + chunk);
    for (int i = e0 + t; i < e1; i += MSB) {
        int s = src[i], d = dst[i];
        unsigned ud = (unsigned)(d - base);
        unsigned us = (unsigned)(s - base);
        if (ud < (unsigned)RSZ) atomicAdd(&hin[ud >> 2], 1u << ((ud & 3) * 8));
        if (us < (unsigned)RSZ) atomicAdd(&hsrc[us >> 2], 1u << ((us & 3) * 8));
    }
    __syncthreads();
    int lim = min(RSZ, n - base);
    if (lim <= 0) return;
    int plim = (lim + 3) >> 2;
    unsigned* gin  = rep_in  + (size_t)c * nwords + (base >> 2);
    unsigned* gsrc = rep_src + (size_t)c * nwords + (base >> 2);
    for (int w = t; w < plim; w += MSB) { gin[w] = hin[w]; gsrc[w] = hsrc[w]; }
}

__global__ __launch_bounds__(256) void k_msreduce(const unsigned* __restrict__ rep_in,
                                                  unsigned* __restrict__ rep_src,   // -> pref
                                                  float* __restrict__ dinv,
                                                  unsigned* __restrict__ counts_src,
                                                  int n, int nwords) {
    int i4 = blockIdx.x * 256 + threadIdx.x;
    if (i4 >= nwords) return;
    unsigned s0 = 0, s1 = 0, s2 = 0, s3 = 0;
    unsigned r0 = 0, r1 = 0, r2 = 0, r3 = 0;
#pragma unroll 4
    for (int c = 0; c < NC_MS; ++c) {
        unsigned vi = rep_in[(size_t)c * nwords + i4];
        s0 += vi & 0xFFu; s1 += (vi >> 8) & 0xFFu; s2 += (vi >> 16) & 0xFFu; s3 += vi >> 24;
        unsigned vs = rep_src[(size_t)c * nwords + i4];
        rep_src[(size_t)c * nwords + i4] = r0 | (r1 << 8) | (r2 << 16) | (r3 << 24);
        r0 += vs & 0xFFu; r1 += (vs >> 8) & 0xFFu; r2 += (vs >> 16) & 0xFFu; r3 += vs >> 24;
    }
    int i = i4 * 4;
    unsigned sv[4] = {s0, s1, s2, s3};
    unsigned rv[4] = {r0, r1, r2, r3};
#pragma unroll
    for (int q = 0; q < 4; ++q) {
        if (i + q < n) {
            dinv[i + q] = rsqrtf((float)(sv[q] + 1u));
            counts_src[i + q] = rv[q];
        }
    }
}

// ---------------- 2-level exclusive scan (edge counts) ----------------
__global__ __launch_bounds__(256) void k_blocksum(const unsigned* __restrict__ counts,
                                                  unsigned* __restrict__ partials, int n) {
    __shared__ unsigned s[256];
    int base = blockIdx.x * 1024;
    unsigned sum = 0;
    for (int j = threadIdx.x; j < 1024; j += 256) {
        int i = base + j;
        sum += (i < n) ? counts[i] : 0u;
    }
    s[threadIdx.x] = sum;
    __syncthreads();
    for (int off = 128; off > 0; off >>= 1) {
        if (threadIdx.x < (unsigned)off) s[threadIdx.x] += s[threadIdx.x + off];
        __syncthreads();
    }
    if (threadIdx.x == 0) partials[blockIdx.x] = s[0];
}

__global__ __launch_bounds__(128) void k_scanpartials(unsigned* __restrict__ partials, int nb) {
    __shared__ unsigned s[128];
    int t = threadIdx.x;
    s[t] = (t < nb) ? partials[t] : 0u;
    __syncthreads();
    if (t == 0) {
        unsigned run = 0;
        for (int i = 0; i < nb; ++i) { unsigned v = s[i]; s[i] = run; run += v; }
    }
    __syncthreads();
    if (t < nb) partials[t] = s[t];
}

__global__ __launch_bounds__(256) void k_scanblock(const unsigned* __restrict__ counts,
                                                   const unsigned* __restrict__ partials,
                                                   unsigned* __restrict__ row_start, int n) {
    __shared__ unsigned s[256];
    int base = blockIdx.x * 1024;
    int t = threadIdx.x;
    unsigned v[4];
    unsigned tsum = 0;
#pragma unroll
    for (int j = 0; j < 4; ++j) {
        int i = base + t * 4 + j;
        v[j] = (i < n) ? counts[i] : 0u;
        tsum += v[j];
    }
    s[t] = tsum;
    __syncthreads();
    for (int off = 1; off < 256; off <<= 1) {
        unsigned x = (t >= off) ? s[t - off] : 0u;
        __syncthreads();
        s[t] += x;
        __syncthreads();
    }
    unsigned excl = (t > 0 ? s[t - 1] : 0u) + partials[blockIdx.x];
#pragma unroll
    for (int j = 0; j < 4; ++j) {
        int i = base + t * 4 + j;
        if (i < n) {
            row_start[i] = excl;
            excl += v[j];
            if (i == n - 1) row_start[n] = excl;
        }
    }
}

// ---------------- edge multi-split fill (u8 LDS cursors) ----------------
__global__ __launch_bounds__(MSB) void k_msfill(const int* __restrict__ src, const int* __restrict__ dst,
                                                const int* __restrict__ batch,
                                                const unsigned* __restrict__ row_start,
                                                const unsigned* __restrict__ pref,
                                                const float* __restrict__ dinv,
                                                uint2* __restrict__ euv,
                                                int e, int n, int chunk, int nwords) {
    __shared__ unsigned cur[RSZP4];
    int c = blockIdx.x % NC_MS;
    int r = blockIdx.x / NC_MS;
    int base = r * RSZ;
    int t = threadIdx.x;
    for (int w = t; w < RSZP4; w += MSB) cur[w] = 0u;
    __syncthreads();
    int e0 = c * chunk, e1 = min(e, e0 + chunk);
    const unsigned* prefc = pref + (size_t)c * nwords;
    for (int i = e0 + t; i < e1; i += MSB) {
        int s = src[i];
        unsigned us = (unsigned)(s - base);
        if (us < (unsigned)RSZ) {
            int d = dst[i];
            unsigned sh = (us & 3) * 8;
            unsigned old = atomicAdd(&cur[us >> 2], 1u << sh);
            unsigned slot = (old >> sh) & 0xFFu;
            unsigned p8 = (prefc[(unsigned)s >> 2] >> ((s & 3) * 8)) & 0xFFu;
            unsigned pos = row_start[s] + p8 + slot;
            uint2 pv;
            pv.x = (unsigned)d | ((unsigned)batch[d] << 17);
            pv.y = f_as_u(dinv[s] * dinv[d]);
            euv[pos] = pv;
        }
    }
}

// ---------------- fused x histograms: word device counts + atom LDS hist ----------------
__global__ __launch_bounds__(256) void k_xcount(const int* __restrict__ x,
                                                unsigned* __restrict__ wcnt,
                                                unsigned* __restrict__ rep_a,
                                                int n, int chunk) {
    __shared__ unsigned h[NATOM];
    int c = blockIdx.x;
    int t = threadIdx.x;
    if (t < NATOM) h[t] = 0u;
    __syncthreads();
    int j0 = c * chunk, j1 = min(n, j0 + chunk);
    for (int j = j0 + t; j < j1; j += 256) {
        int2 xv = *(const int2*)&x[2 * j];   // .x = atom, .y = word
        atomicAdd(&h[xv.x], 1u);
        atomicAdd(&wcnt[xv.y], 1u);
    }
    __syncthreads();
    if (t < NATOM) rep_a[c * NATOM + t] = h[t];
}

// ---------------- fused scans: word scan (1024 thr) + atom chunk-prefix + gstart ----------------
__global__ __launch_bounds__(1024) void k_scanall(const unsigned* __restrict__ wcnt,
                                                  unsigned* __restrict__ wstart,
                                                  unsigned* __restrict__ rep_a,
                                                  unsigned* __restrict__ astart,
                                                  const int* __restrict__ batch,
                                                  int* __restrict__ gstart, int n) {
    __shared__ unsigned s[1024];
    __shared__ unsigned tot[NATOM];
    int t = threadIdx.x;
    // atom per-chunk exclusive prefix (in place)
    if (t < NATOM) {
        unsigned run = 0;
        for (int c = 0; c < NC_A; ++c) {
            unsigned v = rep_a[c * NATOM + t];
            rep_a[c * NATOM + t] = run;
            run += v;
        }
        tot[t] = run;
    }
    // graph boundaries (batch sorted)
    if (t <= NGRAPH_C) {
        if (t == NGRAPH_C) gstart[t] = n;
        else {
            int lo = 0, hi = n;
            while (lo < hi) {
                int mid = (lo + hi) >> 1;
                if (batch[mid] < t) lo = mid + 1; else hi = mid;
            }
            gstart[t] = lo;
        }
    }
    // word scan: 1000 threads x 10
    int lo10 = t * 10;
    unsigned v[10];
    unsigned sum = 0;
    if (lo10 < VOC) {
#pragma unroll
        for (int q = 0; q < 10; ++q) { v[q] = wcnt[lo10 + q]; sum += v[q]; }
    }
    s[t] = sum;
    __syncthreads();
    for (int off = 1; off < 1024; off <<= 1) {
        unsigned xx = (t >= off) ? s[t - off] : 0u;
        __syncthreads();
        s[t] += xx;
        __syncthreads();
    }
    if (lo10 < VOC) {
        unsigned excl = (t > 0) ? s[t - 1] : 0u;
#pragma unroll
        for (int q = 0; q < 10; ++q) { wstart[lo10 + q] = excl; excl += v[q]; }
    }
    if (t == 1023) wstart[VOC] = s[1023];
    if (t == 0) {
        unsigned run = 0;
        for (int a = 0; a < NATOM; ++a) { astart[a] = run; run += tot[a]; }
        astart[NATOM] = run;   // == n
    }
}

// ---------------- fused fills: word cursor scatter + atom LDS-cursor scatter ----------------
__global__ __launch_bounds__(256) void k_xfill(const int* __restrict__ x,
                                               const unsigned* __restrict__ wstart,
                                               unsigned* __restrict__ wcur,
                                               unsigned* __restrict__ sorted,
                                               const unsigned* __restrict__ astart,
                                               const unsigned* __restrict__ rep_a,
                                               unsigned* __restrict__ asorted,
                                               int n, int chunk) {
    __shared__ unsigned cur[NATOM];
    __shared__ unsigned base[NATOM];
    int c = blockIdx.x;
    int t = threadIdx.x;
    if (t < NATOM) {
        cur[t] = 0u;
        base[t] = astart[t] + rep_a[c * NATOM + t];
    }
    __syncthreads();
    int j0 = c * chunk, j1 = min(n, j0 + chunk);
    for (int j = j0 + t; j < j1; j += 256) {
        int2 xv = *(const int2*)&x[2 * j];
        unsigned slot = atomicAdd(&cur[xv.x], 1u);
        asorted[base[xv.x] + slot] = (unsigned)j;
        unsigned pos = wstart[xv.y] + atomicAdd(&wcur[xv.y], 1u);
        sorted[pos] = (unsigned)j;
    }
}

// ---------------- hop 1 (fp16 out, 4-wide unrolled edge loop) ----------------
__global__ __launch_bounds__(256) void k_y1(const int* __restrict__ batch,
                                            const float* __restrict__ dinv,
                                            const unsigned* __restrict__ row_start,
                                            const uint2* __restrict__ euv,
                                            __half* __restrict__ Y1, int n) {
    int idx = blockIdx.x * 256 + threadIdx.x;
    if (idx >= n * 16) return;
    int j = idx >> 4;
    int c4 = idx & 15;
    int cb = c4 * 4;
    float a0 = 0.f, a1 = 0.f, a2 = 0.f, a3 = 0.f;
    {
        int bj = batch[j];
        float dj = dinv[j];
        float sn = dj * dj;
        a0 += (bj == cb + 0) ? sn : 0.f;
        a1 += (bj == cb + 1) ? sn : 0.f;
        a2 += (bj == cb + 2) ? sn : 0.f;
        a3 += (bj == cb + 3) ? sn : 0.f;
    }
    unsigned e0 = row_start[j], e1 = row_start[j + 1];
    unsigned e = e0;
    for (; e + 4 <= e1; e += 4) {
        uint2 p0 = euv[e], p1 = euv[e + 1], p2 = euv[e + 2], p3 = euv[e + 3];
        int b0 = (int)(p0.x >> 17), b1 = (int)(p1.x >> 17);
        int b2 = (int)(p2.x >> 17), b3 = (int)(p3.x >> 17);
        float v0 = u_as_f(p0.y), v1 = u_as_f(p1.y);
        float v2 = u_as_f(p2.y), v3 = u_as_f(p3.y);
        a0 += ((b0 == cb + 0) ? v0 : 0.f) + ((b1 == cb + 0) ? v1 : 0.f)
            + ((b2 == cb + 0) ? v2 : 0.f) + ((b3 == cb + 0) ? v3 : 0.f);
        a1 += ((b0 == cb + 1) ? v0 : 0.f) + ((b1 == cb + 1) ? v1 : 0.f)
            + ((b2 == cb + 1) ? v2 : 0.f) + ((b3 == cb + 1) ? v3 : 0.f);
        a2 += ((b0 == cb + 2) ? v0 : 0.f) + ((b1 == cb + 2) ? v1 : 0.f)
            + ((b2 == cb + 2) ? v2 : 0.f) + ((b3 == cb + 2) ? v3 : 0.f);
        a3 += ((b0 == cb + 3) ? v0 : 0.f) + ((b1 == cb + 3) ? v1 : 0.f)
            + ((b2 == cb + 3) ? v2 : 0.f) + ((b3 == cb + 3) ? v3 : 0.f);
    }
    for (; e < e1; ++e) {
        uint2 p = euv[e];
        int bd = (int)(p.x >> 17);
        float v = u_as_f(p.y);
        a0 += (bd == cb + 0) ? v : 0.f;
        a1 += (bd == cb + 1) ? v : 0.f;
        a2 += (bd == cb + 2) ? v : 0.f;
        a3 += (bd == cb + 3) ? v : 0.f;
    }
    H4 o;
    o.h[0] = __float2half(a0); o.h[1] = __float2half(a1);
    o.h[2] = __float2half(a2); o.h[3] = __float2half(a3);
    *(uint2*)&Y1[(size_t)j * NG + cb] = o.u2;
}

// ---------------- Y-hop fp16 -> fp16 (4-wide unrolled gather for MLP) ----------------
__global__ __launch_bounds__(256) void k_yprop(const __half* __restrict__ Yin,
                                               const float* __restrict__ dinv,
                                               const unsigned* __restrict__ row_start,
                                               const uint2* __restrict__ euv,
                                               __half* __restrict__ Yout, int n) {
    int idx = blockIdx.x * 256 + threadIdx.x;
    if (idx >= n * 16) return;
    int j = idx >> 4;
    int c4 = idx & 15;
    int cb = c4 * 4;
    float dj = dinv[j];
    float sn = dj * dj;
    H4 s; s.u2 = *(const uint2*)&Yin[(size_t)j * NG + cb];
    float a0 = sn * __half2float(s.h[0]);
    float a1 = sn * __half2float(s.h[1]);
    float a2 = sn * __half2float(s.h[2]);
    float a3 = sn * __half2float(s.h[3]);
    unsigned e0 = row_start[j], e1 = row_start[j + 1];
    unsigned e = e0;
    for (; e + 4 <= e1; e += 4) {
        uint2 p0 = euv[e], p1 = euv[e + 1], p2 = euv[e + 2], p3 = euv[e + 3];
        float v0 = u_as_f(p0.y), v1 = u_as_f(p1.y);
        float v2 = u_as_f(p2.y), v3 = u_as_f(p3.y);
        H4 m0; m0.u2 = *(const uint2*)&Yin[(size_t)(p0.x & 0x1FFFFu) * NG + cb];
        H4 m1; m1.u2 = *(const uint2*)&Yin[(size_t)(p1.x & 0x1FFFFu) * NG + cb];
        H4 m2; m2.u2 = *(const uint2*)&Yin[(size_t)(p2.x & 0x1FFFFu) * NG + cb];
        H4 m3; m3.u2 = *(const uint2*)&Yin[(size_t)(p3.x & 0x1FFFFu) * NG + cb];
        a0 += v0 * __half2float(m0.h[0]) + v1 * __half2float(m1.h[0])
            + v2 * __half2float(m2.h[0]) + v3 * __half2float(m3.h[0]);
        a1 += v0 * __half2float(m0.h[1]) + v1 * __half2float(m1.h[1])
            + v2 * __half2float(m2.h[1]) + v3 * __half2float(m3.h[1]);
        a2 += v0 * __half2float(m0.h[2]) + v1 * __half2float(m1.h[2])
            + v2 * __half2float(m2.h[2]) + v3 * __half2float(m3.h[2]);
        a3 += v0 * __half2float(m0.h[3]) + v1 * __half2float(m1.h[3])
            + v2 * __half2float(m2.h[3]) + v3 * __half2float(m3.h[3]);
    }
    for (; e < e1; ++e) {
        uint2 p0 = euv[e];
        float v0 = u_as_f(p0.y);
        H4 m0; m0.u2 = *(const uint2*)&Yin[(size_t)(p0.x & 0x1FFFFu) * NG + cb];
        a0 += v0 * __half2float(m0.h[0]);
        a1 += v0 * __half2float(m0.h[1]);
        a2 += v0 * __half2float(m0.h[2]);
        a3 += v0 * __half2float(m0.h[3]);
    }
    H4 o;
    o.h[0] = __float2half(a0); o.h[1] = __float2half(a1);
    o.h[2] = __float2half(a2); o.h[3] = __float2half(a3);
    *(uint2*)&Yout[(size_t)j * NG + cb] = o.u2;
}

// ---------------- column sums (fp16 input), XCC-replicated output ----------------
__global__ __launch_bounds__(256) void k_colsumh(const __half* __restrict__ Y,
                                                 float* __restrict__ su8, int n) {
    __shared__ float red[16][NG];
    int t = threadIdx.x;
    int cg = t & 15;
    int sr = t >> 4;
    float a0 = 0.f, a1 = 0.f, a2 = 0.f, a3 = 0.f;
    int stride = gridDim.x * 16;
    for (int j = blockIdx.x * 16 + sr; j < n; j += stride) {
        H4 v; v.u2 = *(const uint2*)&Y[(size_t)j * NG + cg * 4];
        a0 += __half2float(v.h[0]);
        a1 += __half2float(v.h[1]);
        a2 += __half2float(v.h[2]);
        a3 += __half2float(v.h[3]);
    }
    red[sr][cg * 4 + 0] = a0;
    red[sr][cg * 4 + 1] = a1;
    red[sr][cg * 4 + 2] = a2;
    red[sr][cg * 4 + 3] = a3;
    __syncthreads();
    if (t < NG) {
        float s = 0.f;
#pragma unroll
        for (int q = 0; q < 16; ++q) s += red[q][t];
        int r = xcc_id();
        __hip_atomic_fetch_add(&su8[r * NG + t], s,
                               __ATOMIC_RELAXED, __HIP_MEMORY_SCOPE_WORKGROUP);
    }
}

// ---------------- fused per-vocab column sums: tw (words) + tap (atom slices) ----------------
__global__ __launch_bounds__(256) void k_twta(const __half* __restrict__ Y3,
                                              const unsigned* __restrict__ sorted,
                                              const unsigned* __restrict__ wstart,
                                              float* __restrict__ tw,
                                              const unsigned* __restrict__ asorted,
                                              const unsigned* __restrict__ astart,
                                              float* __restrict__ tap) {
    int t = threadIdx.x;
    int g = t & 63;
    if (blockIdx.x < TW_BLKS) {
        int w = blockIdx.x * 4 + (t >> 6);
        if (w >= VOC) return;
        unsigned i0 = wstart[w], i1 = wstart[w + 1];
        float s = 0.f;
        unsigned i = i0;
        for (; i + 2 <= i1; i += 2) {
            unsigned j0 = sorted[i], j1 = sorted[i + 1];
            s += __half2float(Y3[(size_t)j0 * NG + g]) + __half2float(Y3[(size_t)j1 * NG + g]);
        }
        if (i < i1) s += __half2float(Y3[(size_t)sorted[i] * NG + g]);
        tw[(size_t)w * NG + g] = s;
    } else {
        int wid = (blockIdx.x - TW_BLKS) * 4 + (t >> 6);
        if (wid >= NATOM * ASL) return;
        int a  = wid >> 7;
        int sl = wid & (ASL - 1);
        unsigned i0 = astart[a], i1 = astart[a + 1];
        unsigned len = i1 - i0;
        unsigned lo = i0 + (unsigned)((unsigned long long)len * sl / ASL);
        unsigned hi = i0 + (unsigned)((unsigned long long)len * (sl + 1) / ASL);
        float s = 0.f;
        unsigned i = lo;
        for (; i + 2 <= hi; i += 2) {
            unsigned j0 = asorted[i], j1 = asorted[i + 1];
            s += __half2float(Y3[(size_t)j0 * NG + g]) + __half2float(Y3[(size_t)j1 * NG + g]);
        }
        if (i < hi) s += __half2float(Y3[(size_t)asorted[i] * NG + g]);
        tap[((size_t)a * ASL + sl) * NG + g] = s;
    }
}

// ---------------- tiled word contraction + folded tareduce (bx==5) ----------------
__global__ __launch_bounds__(256) void k_wgemm2(const float* __restrict__ T,    // [KPAD][64]
                                                const float* __restrict__ Tab,  // [10000][300]
                                                float* __restrict__ Gpart,
                                                const float* __restrict__ tap,
                                                float* __restrict__ ta) {
    if (blockIdx.x == 5) {   // tareduce: tap[41][ASL][64] -> ta[41*64]
        int i = blockIdx.y * 256 + threadIdx.x;
        if (i >= NATOM * NG) return;
        int a = i >> 6;
        int g = i & 63;
        float s = 0.f;
        for (int sl = 0; sl < ASL; ++sl) s += tap[((size_t)a * ASL + sl) * NG + g];
        ta[i] = s;
        return;
    }
    __shared__ float Asm[32 * 64];
    __shared__ float Bsm[32 * 64];
    const int t = threadIdx.x;
    const int tg = t >> 4;
    const int tc = t & 15;
    const int c0 = blockIdx.x * 64;
    const int kb = blockIdx.y * WGK;

    float acc[4][4] = {};

    for (int sub = 0; sub < WGK / 32; ++sub) {
        int kbase = kb + sub * 32;
#pragma unroll
        for (int r2 = 0; r2 < 2; ++r2) {
            int idx4 = r2 * 256 + t;
            int k = idx4 >> 4, g4 = idx4 & 15;
            float4 v = *(const float4*)&T[(size_t)(kbase + k) * 64 + g4 * 4];
            *(float4*)&Asm[k * 64 + g4 * 4] = v;
        }
#pragma unroll
        for (int r2 = 0; r2 < 2; ++r2) {
            int idx4 = r2 * 256 + t;
            int k = idx4 >> 4, c4i = idx4 & 15;
            int gk = kbase + k;
            int cb2 = c0 + c4i * 4;
            float4 v;
            if (gk < VOC && cb2 + 3 < 300) {
                v = *(const float4*)&Tab[(size_t)gk * 300 + cb2];
            } else {
                float tmp[4];
#pragma unroll
                for (int q = 0; q < 4; ++q)
                    tmp[q] = (gk < VOC && cb2 + q < 300) ? Tab[(size_t)gk * 300 + cb2 + q] : 0.f;
                v.x = tmp[0]; v.y = tmp[1]; v.z = tmp[2]; v.w = tmp[3];
            }
            *(float4*)&Bsm[k * 64 + c4i * 4] = v;
        }
        __syncthreads();
#pragma unroll 8
        for (int k = 0; k < 32; ++k) {
            float4 a4 = *(const float4*)&Asm[k * 64 + tg * 4];
            float4 b4 = *(const float4*)&Bsm[k * 64 + tc * 4];
            float a[4] = {a4.x, a4.y, a4.z, a4.w};
            float b[4] = {b4.x, b4.y, b4.z, b4.w};
#pragma unroll
            for (int i = 0; i < 4; ++i)
#pragma unroll
                for (int jj = 0; jj < 4; ++jj) acc[i][jj] += a[i] * b[jj];
        }
        __syncthreads();
    }

    float* gp = Gpart + (size_t)blockIdx.y * (NG * 300);
#pragma unroll
    for (int i = 0; i < 4; ++i) {
        int g = tg * 4 + i;
#pragma unroll
        for (int jj = 0; jj < 4; ++jj) {
            int c = c0 + tc * 4 + jj;
            if (c < 300) gp[g * 300 + c] = acc[i][jj];
        }
    }
}

// ---------------- fused: reduce Gpart into G0 (by<8) + atom contraction (by==8) ----------------
__global__ __launch_bounds__(256) void k_gredagemm(const float* __restrict__ Gpart,
                                                   const float* __restrict__ ta,
                                                   const float* __restrict__ at,
                                                   float* __restrict__ G0) {
    int k = blockIdx.x * 256 + threadIdx.x;
    if (k >= NG * 300) return;
    if (blockIdx.y < 8) {
        int p0 = blockIdx.y * (NKC / 8);
        int p1 = p0 + (NKC / 8);
        float s = 0.f;
        for (int p = p0; p < p1; ++p) s += Gpart[(size_t)p * (NG * 300) + k];
        atomicAdd(&G0[k], s);
    } else {
        int g = k / 300, c = k - g * 300;
        float acc = 0.f;
#pragma unroll
        for (int q = 0; q < NATOM; ++q) acc += ta[q * NG + g] * at[(size_t)q * 300 + c];
        atomicAdd(&G0[k], acc);
    }
}

// ---------------- small GEMM split-k + folded vector-matrix (bx>=75) ----------------
__global__ __launch_bounds__(256) void k_smm(const float* __restrict__ A,
                                             const float* __restrict__ W,
                                             float* __restrict__ C,
                                             const float* __restrict__ vin,
                                             float* __restrict__ r_out) {
    int bx = blockIdx.x;
    if (bx >= 75) {   // r_out[c] += sum_k vin[k]*W[k][c], 5 chunks of 60
        int c = (bx - 75) * 256 + threadIdx.x;
        if (c >= 300) return;
        int k0 = blockIdx.y * 60;
        float acc = 0.f;
        for (int k = k0; k < k0 + 60; ++k) acc += vin[k] * W[k * 300 + c];
        atomicAdd(&r_out[c], acc);
        return;
    }
    int j = bx * 256 + threadIdx.x;
    if (j >= NG * 300) return;
    int g = j / 300, c = j - g * 300;
    int k0 = blockIdx.y * 60;
    float acc = 0.f;
#pragma unroll 1
    for (int k = k0; k < k0 + 60; k += 4) {
        float a0 = A[g * 300 + k + 0], a1 = A[g * 300 + k + 1];
        float a2 = A[g * 300 + k + 2], a3 = A[g * 300 + k + 3];
        float w0 = W[(k + 0) * 300 + c], w1 = W[(k + 1) * 300 + c];
        float w2 = W[(k + 2) * 300 + c], w3 = W[(k + 3) * 300 + c];
        acc += a0 * w0 + a1 * w1 + a2 * w2 + a3 * w3;
    }
    atomicAdd(&C[j], acc);
}

// ---------------- final assembly ----------------
__global__ __launch_bounds__(256) void k_out(const float* __restrict__ T3,
                                             const float* __restrict__ su1,
                                             const float* __restrict__ su2,
                                             const int* __restrict__ gstart,
                                             const float* __restrict__ r1,
                                             const float* __restrict__ r2,
                                             const float* __restrict__ b,
                                             float* __restrict__ out) {
    int j = blockIdx.x * 256 + threadIdx.x;
    if (j >= NG * 300) return;
    int g = j / 300, c = j - g * 300;
    int cnt = gstart[g + 1] - gstart[g];
    float s1 = 0.f, s2 = 0.f;
#pragma unroll
    for (int r = 0; r < 8; ++r) {
        s1 += su1[r * NG + g];
        s2 += su2[r * NG + g];
    }
    float v = T3[j] + s2 * r2[c] + s1 * r1[c] + (float)cnt * b[c];
    out[j] = v / (float)(cnt > 0 ? cnt : 1);
}

// ---------------- launch ----------------
extern "C" void kernel_launch(void* const* d_in, const int* in_sizes, int n_in,
                              void* d_out, int out_size, void* d_ws, size_t ws_size,
                              hipStream_t stream) {
    const int*   x     = (const int*)d_in[0];
    const int*   ei    = (const int*)d_in[1];
    const int*   batch = (const int*)d_in[2];
    const float* at    = (const float*)d_in[3];
    const float* wt    = (const float*)d_in[4];
    const float* W     = (const float*)d_in[5];
    const float* b     = (const float*)d_in[6];

    const int n = in_sizes[0] / 2;   // 100000
    const int e = in_sizes[1] / 2;   // 800000

    char* ws = (char*)d_ws;
    size_t off = 0;
    auto carve = [&](size_t bytes) {
        void* p = ws + off;
        off += (bytes + 255) & ~(size_t)255;
        return p;
    };
    __half*   Y1        = (__half*)carve((size_t)n * NG * 2);
    __half*   Y2        = (__half*)carve((size_t)n * NG * 2);
    __half*   Y3        = (__half*)carve((size_t)n * NG * 2);
    uint2*    euv       = (uint2*)carve((size_t)e * 8);
    float*    dinv      = (float*)carve((size_t)n * 4);
    unsigned* counts_src= (unsigned*)carve((size_t)n * 4);
    unsigned* row_start = (unsigned*)carve((size_t)(n + 1) * 4);
    unsigned* partials  = (unsigned*)carve(1024 * 4);
    int*      gstart    = (int*)carve(65 * 4);
    unsigned* wstart    = (unsigned*)carve((size_t)(VOC + 1) * 4);
    unsigned* sorted    = (unsigned*)carve((size_t)n * 4);
    unsigned* asorted   = (unsigned*)carve((size_t)n * 4);
    unsigned* astart    = (unsigned*)carve((NATOM + 1) * 4);
    unsigned* rep_a     = (unsigned*)carve((size_t)NC_A * NATOM * 4);
    float*    tap       = (float*)carve((size_t)NATOM * ASL * NG * 4);  // 1.34 MB
    // ---- zero region B ----
    char*     zB0       = (char*)carve(0);
    float*    su1       = (float*)carve((size_t)8 * NG * 4);
    float*    su2       = (float*)carve((size_t)8 * NG * 4);
    float*    ta        = (float*)carve((size_t)NATOM * NG * 4);
    float*    tw        = (float*)carve((size_t)KPAD * NG * 4);   // pad rows must be zero
    float*    G0        = (float*)carve((size_t)NG * 300 * 4);
    float*    r1        = (float*)carve(300 * 4);
    float*    r2        = (float*)carve(300 * 4);
    float*    T1        = (float*)carve((size_t)NG * 300 * 4);
    float*    T2        = (float*)carve((size_t)NG * 300 * 4);
    float*    T3        = (float*)carve((size_t)NG * 300 * 4);
    unsigned* wcnt      = (unsigned*)carve((size_t)VOC * 4);
    unsigned* wcur      = (unsigned*)carve((size_t)VOC * 4);
    char*     zB1       = (char*)carve(0);

    const int* src = ei;
    const int* dst = ei + e;

    // aliases (lifetime-disjoint):
    //  u8 edge replicas (NC_MS * n = 12.8 MB each) in Y1/Y2 (dead before k_y1 / yprop#1 write them)
    //  Gpart (80*19200*4 = 6.1 MB) in Y1 (Y1 dead after yprop#1 reads it)
    unsigned* rep_in  = (unsigned*)Y1;
    unsigned* rep_src = (unsigned*)Y2;
    float*    Gpart   = (float*)Y1;

    hipMemsetAsync(zB0, 0, (size_t)(zB1 - zB0), stream);

    const int nwords = (n + 3) / 4;                // u8-packed words per chunk
    const int chunk  = (e + NC_MS - 1) / NC_MS;    // 6250
    const int achunk = (n + NC_A - 1) / NC_A;      // 782

    // edge reverse-CSR (u8 multi-split)
    k_mscount<<<NRNG * NC_MS, MSB, 0, stream>>>(src, dst, rep_in, rep_src, e, n, chunk, nwords);
    k_msreduce<<<(nwords + 255) / 256, 256, 0, stream>>>(rep_in, rep_src, dinv, counts_src, n, nwords);
    int NB = (n + 1023) / 1024;      // 98
    k_blocksum<<<NB, 256, 0, stream>>>(counts_src, partials, n);
    k_scanpartials<<<1, 128, 0, stream>>>(partials, NB);
    k_scanblock<<<NB, 256, 0, stream>>>(counts_src, partials, row_start, n);
    k_msfill<<<NRNG * NC_MS, MSB, 0, stream>>>(src, dst, batch, row_start, rep_src, dinv, euv, e, n, chunk, nwords);

    // fused vocab sorts: one x pass for both histograms, one combined scan, one fill pass
    k_xcount<<<NC_A, 256, 0, stream>>>(x, wcnt, rep_a, n, achunk);
    k_scanall<<<1, 1024, 0, stream>>>(wcnt, wstart, rep_a, astart, batch, gstart, n);
    k_xfill<<<NC_A, 256, 0, stream>>>(x, wstart, wcur, sorted, astart, rep_a, asorted, n, achunk);

    // indicator propagation: Y1 -> Y2 -> Y3 (fp16)
    int yb = (n * 16 + 255) / 256;   // 6250
    k_y1<<<yb, 256, 0, stream>>>(batch, dinv, row_start, euv, Y1, n);
    k_colsumh<<<512, 256, 0, stream>>>(Y1, su1, n);
    k_yprop<<<yb, 256, 0, stream>>>(Y1, dinv, row_start, euv, Y2, n);
    k_colsumh<<<512, 256, 0, stream>>>(Y2, su2, n);
    k_yprop<<<yb, 256, 0, stream>>>(Y2, dinv, row_start, euv, Y3, n);

    // contractions -> G0 = Y3^T H0
    k_twta<<<TW_BLKS + TA_BLKS, 256, 0, stream>>>(Y3, sorted, wstart, tw, asorted, astart, tap);
    {
        dim3 gw(6, NKC);   // bx<5: 5 c-tiles x 80 k-chunks; bx==5: tareduce (by<11 used)
        k_wgemm2<<<gw, 256, 0, stream>>>(tw, wt, Gpart, tap, ta);
        dim3 gr((NG * 300 + 255) / 256, 9);   // by<8: greduce; by==8: agemm
        k_gredagemm<<<gr, 256, 0, stream>>>(Gpart, ta, at, G0);
    }

    // W chain: T3 = G0 * W^3 (vec chain folded into first two launches)
    {
        dim3 gs1(77, 5);
        k_smm<<<gs1, 256, 0, stream>>>(G0, W, T1, b, r1);    // T1 = G0*W, r1 = b*W
        k_smm<<<gs1, 256, 0, stream>>>(T1, W, T2, r1, r2);   // T2 = T1*W, r2 = r1*W
        dim3 gs3(75, 5);
        k_smm<<<gs3, 256, 0, stream>>>(T2, W, T3, r2, r2);   // T3 = T2*W (no vec part)
    }

    k_out<<<(NG * 300 + 255) / 256, 256, 0, stream>>>(T3, su1, su2, gstart, r1, r2, b, (float*)d_out);
}